// Round 6
// baseline (799.879 us; speedup 1.0000x reference)
//
#include <hip/hip_runtime.h>
#include <hip/hip_bf16.h>
#include <stdint.h>

#define SUPPORT 10
#define KNN 20
#define DEGREE 8

// ---------------------------------------------------------------------------
// prep: normalize all 6 direction matrices (columns over axis 0, sequential
// non-FMA to match np), collapse w_l1 @ w_l2 -> 64x3 (fast pc2 path), and
// transpose pts1 to SoA (px1/py1/pz1) for coalesced kNN loads.
// grid: 19 blocks x 256
// ---------------------------------------------------------------------------
__global__ __launch_bounds__(256) void prep_kernel(
    const float* __restrict__ d0, const float* __restrict__ dir1,
    const float* __restrict__ d2, const float* __restrict__ dir3,
    const float* __restrict__ dir4, const float* __restrict__ dir5,
    float* __restrict__ sdn0, float* __restrict__ sdn1, float* __restrict__ sdn2,
    float* __restrict__ sdn3, float* __restrict__ sdn4, float* __restrict__ sdn5,
    const float* __restrict__ l1a, const float* __restrict__ l1b,
    const float* __restrict__ l2a, const float* __restrict__ l2b,
    float* __restrict__ wc1, float* __restrict__ wc2,
    const float* __restrict__ pts1,
    float* __restrict__ px1, float* __restrict__ py1, float* __restrict__ pz1) {
#pragma clang fp contract(off)
  if (blockIdx.x < 13) {
    int t = blockIdx.x * 256 + threadIdx.x;
    if (t >= 3200) return;
    const float* src; float* dst; int cols; int e;
    if (t < 320)       { src = d0;   dst = sdn0; cols = 320; e = t; }
    else if (t < 960)  { src = dir1; dst = sdn1; cols = 640; e = t - 320; }
    else if (t < 1280) { src = d2;   dst = sdn2; cols = 320; e = t - 960; }
    else if (t < 1920) { src = dir3; dst = sdn3; cols = 640; e = t - 1280; }
    else if (t < 2560) { src = dir4; dst = sdn4; cols = 640; e = t - 1920; }
    else               { src = dir5; dst = sdn5; cols = 640; e = t - 2560; }
    float a = src[e], b = src[cols + e], c = src[2 * cols + e];
    float nrm = sqrtf(a * a + b * b + c * c);
    nrm = fmaxf(nrm, 1e-12f);
    dst[e] = a / nrm; dst[cols + e] = b / nrm; dst[2 * cols + e] = c / nrm;
  } else if (blockIdx.x < 15) {
    int which = blockIdx.x - 13;          // 0 -> wc1, 1 -> wc2
    int tt = threadIdx.x;
    if (tt >= 192) return;
    const float* A  = which ? l2a : l1a;  // (64, 640)
    const float* Bm = which ? l2b : l1b;  // (640, 3)
    float* out = which ? wc2 : wc1;
    int i = tt / 3, c = tt % 3;
    float s = 0.f;
    for (int k = 0; k < 640; ++k) s = fmaf(A[i * 640 + k], Bm[k * 3 + c], s);
    out[i * 3 + c] = s;
  } else {
    int t = (blockIdx.x - 15) * 256 + threadIdx.x;  // 0..1023 over 2*512 pts
    if (t >= 1024) return;
    px1[t] = pts1[t * 3];
    py1[t] = pts1[t * 3 + 1];
    pz1[t] = pts1[t * 3 + 2];
  }
}

// ---------------------------------------------------------------------------
// soa2: transpose pc1 (2,4096,3) into SoA for stage-2 kNN.
// ---------------------------------------------------------------------------
__global__ __launch_bounds__(256) void soa2_kernel(const float* __restrict__ pc1,
                                                   float* __restrict__ px,
                                                   float* __restrict__ py,
                                                   float* __restrict__ pz) {
  int t = blockIdx.x * 256 + threadIdx.x;
  if (t >= 8192) return;
  px[t] = pc1[t * 3];
  py[t] = pc1[t * 3 + 1];
  pz[t] = pc1[t * 3 + 2];
}

// ---------------------------------------------------------------------------
// sorted insert of key into ascending 4-register list (t0 smallest).
// ---------------------------------------------------------------------------
__device__ __forceinline__ void ins4(unsigned long long key,
                                     unsigned long long& t0, unsigned long long& t1,
                                     unsigned long long& t2, unsigned long long& t3) {
  if (key < t3) {
    if (key < t2) {
      t3 = t2;
      if (key < t1) {
        t2 = t1;
        if (key < t0) { t1 = t0; t0 = key; } else { t1 = key; }
      } else { t2 = key; }
    } else { t3 = key; }
  }
}

// ---------------------------------------------------------------------------
// kNN, LDS-free: one wave per query. Lane l owns stripe {m : m ≡ l (mod 64)}
// and keeps its 4 smallest packed keys (flipped-dist-bits<<32 | m) in sorted
// registers (invariant: t0 == exact min of lane's remaining stripe). 21
// rounds of one wave-min butterfly; winner's lane pops; a lane that drains
// its 4 refills by recomputing its stripe (bit-identical distance formula,
// popped elements masked). Round 0 (self) dropped; rounds 1..20 reproduce
// jax.lax.top_k(-dist) order incl. stable tie-break exactly.
// Distance math sequential non-FMA = bit-identical to np einsum.
// ---------------------------------------------------------------------------
template <int MPER, int WAVES>
__global__ __launch_bounds__(WAVES * 64) void knn_kernel(
    const float* __restrict__ px, const float* __restrict__ py,
    const float* __restrict__ pz, int N, int* __restrict__ idx_out) {
#pragma clang fp contract(off)
  int w = threadIdx.x >> 6, lane = threadIdx.x & 63;
  int g = blockIdx.x * WAVES + w;           // global node id in [0, 2N)
  int b = g / N, n = g % N;
  const float* PX = px + (size_t)b * N;
  const float* PY = py + (size_t)b * N;
  const float* PZ = pz + (size_t)b * N;

  float nx = PX[n], ny = PY[n], nz = PZ[n];
  float qn = nx * nx + ny * ny + nz * nz;

  unsigned long long t0 = ~0ull, t1 = ~0ull, t2 = ~0ull, t3 = ~0ull;
  unsigned long long popmask = 0ull;

  for (int j = 0; j < MPER; ++j) {
    int m = j * 64 + lane;
    float mx = PX[m], my = PY[m], mz = PZ[m];
    float inner = nx * mx + ny * my + nz * mz;
    float qm = mx * mx + my * my + mz * mz;
    float d = (qn - 2.0f * inner) + qm;
    uint32_t u = __float_as_uint(d);
    u ^= (u & 0x80000000u) ? 0xFFFFFFFFu : 0x80000000u;  // order-preserving flip
    ins4(((unsigned long long)u << 32) | (unsigned)m, t0, t1, t2, t3);
  }

  for (int r = 0; r < 21; ++r) {
    unsigned long long best = t0;
#pragma unroll
    for (int s = 1; s < 64; s <<= 1) {
      unsigned long long o = __shfl_xor(best, s, 64);
      best = o < best ? o : best;
    }
    unsigned m = (unsigned)best;
    if (r > 0 && lane == 0) idx_out[(size_t)g * KNN + (r - 1)] = (int)m;
    if (r == 20) break;
    int owner = m & 63, jwin = m >> 6;
    if (lane == owner) {
      popmask |= 1ull << jwin;
      t0 = t1; t1 = t2; t2 = t3; t3 = ~0ull;
    }
    bool dry = (t0 == ~0ull) && (__builtin_popcountll(popmask) < MPER);
    if (__any(dry)) {
      if (dry) {
        t1 = t2 = t3 = ~0ull;
        for (int j = 0; j < MPER; ++j) {
          if ((popmask >> j) & 1ull) continue;
          int mm = j * 64 + lane;
          float mx = PX[mm], my = PY[mm], mz = PZ[mm];
          float inner = nx * mx + ny * my + nz * mz;
          float qm = mx * mx + my * my + mz * mz;
          float d = (qn - 2.0f * inner) + qm;
          uint32_t u = __float_as_uint(d);
          u ^= (u & 0x80000000u) ? 0xFFFFFFFFu : 0x80000000u;
          ins4(((unsigned long long)u << 32) | (unsigned)mm, t0, t1, t2, t3);
        }
      }
    }
  }
}

// ---------------------------------------------------------------------------
// ndn: normalized neighbor directions (sequential non-FMA, matches np).
// ---------------------------------------------------------------------------
__global__ __launch_bounds__(256) void ndn_kernel(const float* __restrict__ pts,
                                                  const int* __restrict__ idx,
                                                  float* __restrict__ ndn, int N) {
#pragma clang fp contract(off)
  int t = blockIdx.x * 256 + threadIdx.x;
  int total = 2 * N * KNN;
  if (t >= total) return;
  int k = t % KNN, g = t / KNN;
  int b = g / N, n = g % N;
  int m = idx[(size_t)g * KNN + k];
  const float* pb = pts + (size_t)b * N * 3;
  float dx = pb[m * 3] - pb[n * 3];
  float dy = pb[m * 3 + 1] - pb[n * 3 + 1];
  float dz = pb[m * 3 + 2] - pb[n * 3 + 2];
  float nr = sqrtf(dx * dx + dy * dy + dz * dz);
  nr = fmaxf(nr, 1e-12f);
  ndn[(size_t)t * 3] = dx / nr; ndn[(size_t)t * 3 + 1] = dy / nr; ndn[(size_t)t * 3 + 2] = dz / nr;
}

// ---------------------------------------------------------------------------
// op3d: out[g,c] = sum_s max_k relu(ndn[g,k]·sdn[:, s*32+c]); half-wave/node.
// ---------------------------------------------------------------------------
__global__ __launch_bounds__(256) void op3d_kernel(const float* __restrict__ ndn,
                                                   const float* __restrict__ sdn,
                                                   float* __restrict__ out, int N) {
#pragma clang fp contract(off)
  int c = threadIdx.x & 31;
  int g = (blockIdx.x * 256 + threadIdx.x) >> 5;
  if (g >= 2 * N) return;
  const float* nd = ndn + (size_t)g * 60;
  float sv0[SUPPORT], sv1[SUPPORT], sv2[SUPPORT], mm[SUPPORT];
#pragma unroll
  for (int s = 0; s < SUPPORT; ++s) {
    sv0[s] = sdn[s * 32 + c];
    sv1[s] = sdn[320 + s * 32 + c];
    sv2[s] = sdn[640 + s * 32 + c];
    mm[s] = 0.f;  // == max over relu'd values
  }
  for (int k = 0; k < KNN; ++k) {
    float nx = nd[k * 3], ny = nd[k * 3 + 1], nz = nd[k * 3 + 2];
#pragma unroll
    for (int s = 0; s < SUPPORT; ++s) {
      float t = nx * sv0[s] + ny * sv1[s] + nz * sv2[s];
      mm[s] = fmaxf(mm[s], t);
    }
  }
  float acc = 0.f;
#pragma unroll
  for (int s = 0; s < SUPPORT; ++s) acc += mm[s];
  out[(size_t)g * 32 + c] = acc;  // outer relu is a no-op (acc >= 0)
}

// ---------------------------------------------------------------------------
// fo = feat @ W + b: sequential-k fmaf chain per element (matches BLAS).
// Block handles 8 nodes for W reuse from L2.
// ---------------------------------------------------------------------------
template <int K>
__global__ __launch_bounds__(256) void fo_kernel(const float* __restrict__ feat,
                                                 const float* __restrict__ wmat,
                                                 const float* __restrict__ bias,
                                                 float* __restrict__ fo, int N) {
  __shared__ float fL[8 * K];
  int t = threadIdx.x;
  int gbase = blockIdx.x * 8;
  for (int i = t; i < 8 * K; i += 256) fL[i] = feat[(size_t)gbase * K + i];
  __syncthreads();
  float a0[8], a1[8], a2[8];
#pragma unroll
  for (int gg = 0; gg < 8; ++gg) { a0[gg] = 0.f; a1[gg] = 0.f; a2[gg] = 0.f; }
  bool has3 = (t < 192);
  for (int i = 0; i < K; ++i) {
    float w0 = wmat[i * 704 + t];
    float w1 = wmat[i * 704 + t + 256];
    float w2 = has3 ? wmat[i * 704 + t + 512] : 0.f;
#pragma unroll
    for (int gg = 0; gg < 8; ++gg) {
      float f = fL[gg * K + i];
      a0[gg] = fmaf(f, w0, a0[gg]);
      a1[gg] = fmaf(f, w1, a1[gg]);
      a2[gg] = fmaf(f, w2, a2[gg]);
    }
  }
  float b0 = bias[t], b1 = bias[t + 256], b2 = has3 ? bias[t + 512] : 0.f;
#pragma unroll
  for (int gg = 0; gg < 8; ++gg) {
    size_t base = (size_t)(gbase + gg) * 704;
    fo[base + t] = a0[gg] + b0;
    fo[base + t + 256] = a1[gg] + b1;
    if (has3) fo[base + t + 512] = a2[gg] + b2;
  }
}

// ---------------------------------------------------------------------------
// opnd: one wave per node, lane = output channel (64). Natural block order
// (R5's XCD swizzle suspected regression — reverted for bisect).
// ---------------------------------------------------------------------------
__global__ __launch_bounds__(256) void opnd_kernel(const float* __restrict__ ndn,
                                                   const int* __restrict__ idx,
                                                   const float* __restrict__ fo,
                                                   const float* __restrict__ sdn,
                                                   float* __restrict__ fm, int N) {
#pragma clang fp contract(off)
  __shared__ float ndL[4][64];
  __shared__ int offL[4][24];
  int w = threadIdx.x >> 6, lane = threadIdx.x & 63;
  int g = blockIdx.x * 4 + w;
  if (lane < 60) ndL[w][lane] = ndn[(size_t)g * 60 + lane];
  if (lane < KNN) offL[w][lane] = ((g / N) * N + idx[(size_t)g * KNN + lane]) * 704 + 64;
  __syncthreads();
  const float* ndw = ndL[w];
  const int* offw = offL[w];
  float sv0[SUPPORT], sv1[SUPPORT], sv2[SUPPORT], mm[SUPPORT];
#pragma unroll
  for (int s = 0; s < SUPPORT; ++s) {
    sv0[s] = sdn[s * 64 + lane];
    sv1[s] = sdn[640 + s * 64 + lane];
    sv2[s] = sdn[1280 + s * 64 + lane];
    mm[s] = -__builtin_inff();
  }
  for (int k = 0; k < KNN; ++k) {
    float nx = ndw[k * 3], ny = ndw[k * 3 + 1], nz = ndw[k * 3 + 2];
    int off = offw[k];
#pragma unroll
    for (int s = 0; s < SUPPORT; ++s) {
      float t = fmaxf(nx * sv0[s] + ny * sv1[s] + nz * sv2[s], 0.f);
      float f = fo[(size_t)off + s * 64 + lane];
      mm[s] = fmaxf(mm[s], t * f);
    }
  }
  float acc = 0.f;
#pragma unroll
  for (int s = 0; s < SUPPORT; ++s) acc += mm[s];
  float fc = fo[(size_t)g * 704 + lane];
  float v = fc + acc;
  fm[(size_t)g * 64 + lane] = fmaxf(v, 0.f);
}

// ---------------------------------------------------------------------------
// tree_gcn EXACT (pc1 only): mirrors np op-by-op; bit-identical element
// arithmetic (pc1 feeds stage-2 kNN so this must track np).
// ---------------------------------------------------------------------------
__global__ __launch_bounds__(256) void tree_exact_kernel(
    const float* __restrict__ x, const float* __restrict__ wroot,
    const float* __restrict__ wb, const float* __restrict__ l1,
    const float* __restrict__ l2, const float* __restrict__ bias,
    float* __restrict__ out, int node) {
#pragma clang fp contract(off)
  __shared__ float xL[2][64];
  __shared__ float brL[2][512];
  __shared__ float tL[16][640];
  __shared__ float rootv[2][3];
  int n = blockIdx.x, t = threadIdx.x;
  if (t < 128) xL[t >> 6][t & 63] = x[(size_t)(t >> 6) * node * 64 + (size_t)n * 64 + (t & 63)];
  __syncthreads();
  {
    const float* wrow = wb + (size_t)n * 64 * 512;
    int j0 = 2 * t;
    float a00 = 0.f, a01 = 0.f, a10 = 0.f, a11 = 0.f;
    for (int i = 0; i < 64; ++i) {
      float w0 = wrow[(size_t)i * 512 + j0];
      float w1 = wrow[(size_t)i * 512 + j0 + 1];
      float f0 = xL[0][i], f1 = xL[1][i];
      a00 = a00 + f0 * w0; a01 = a01 + f0 * w1;
      a10 = a10 + f1 * w0; a11 = a11 + f1 * w1;
    }
    brL[0][j0]     = a00 >= 0.f ? a00 : 0.2f * a00;
    brL[0][j0 + 1] = a01 >= 0.f ? a01 : 0.2f * a01;
    brL[1][j0]     = a10 >= 0.f ? a10 : 0.2f * a10;
    brL[1][j0 + 1] = a11 >= 0.f ? a11 : 0.2f * a11;
  }
  if (t < 6) {
    int b = t / 3, c = t % 3;
    float r = 0.f;
    for (int i = 0; i < 64; ++i) r = fmaf(xL[b][i], wroot[i * 3 + c], r);
    rootv[b][c] = r;
  }
  __syncthreads();
#pragma unroll 4
  for (int u = 0; u < 40; ++u) {        // 16*640 / 256
    int e = u * 256 + t;
    int p = e / 640, j = e % 640;       // p: b = p>>3, d = p&7
    const float* brow = brL[p >> 3] + (p & 7) * 64;
    float acc = 0.f;
    for (int i = 0; i < 64; ++i)
      acc = fmaf(brow[i], l1[i * 640 + j], acc);
    tL[p][j] = acc;
  }
  __syncthreads();
  if (t < 48) {
    int p = t / 3, c = t % 3, b = p >> 3, d = p & 7;
    float s = 0.f;
    for (int j = 0; j < 640; ++j) s = fmaf(tL[p][j], l2[j * 3 + c], s);
    float v = rootv[b][c] + s;
    v = v + bias[d * 3 + c];
    v = v >= 0.f ? v : 0.2f * v;
    out[((size_t)b * node * DEGREE + (size_t)n * DEGREE + d) * 3 + c] = v;
  }
}

// ---------------------------------------------------------------------------
// tree_gcn FAST (pc2): collapsed w_l1@w_l2, HBM-bound on w_branch stream.
// ---------------------------------------------------------------------------
__global__ __launch_bounds__(256) void tree_kernel(const float* __restrict__ x,
                                                   const float* __restrict__ wroot,
                                                   const float* __restrict__ wb,
                                                   const float* __restrict__ wc,
                                                   float* __restrict__ out,
                                                   int node) {
  __shared__ float xL[2][64];
  __shared__ float brL[2][512];
  int n = blockIdx.x;
  int t = threadIdx.x;
  if (t < 128) xL[t >> 6][t & 63] = x[(size_t)(t >> 6) * node * 64 + (size_t)n * 64 + (t & 63)];
  __syncthreads();
  float a00 = 0.f, a01 = 0.f, a10 = 0.f, a11 = 0.f;
  const float* wrow = wb + (size_t)n * 64 * 512;
  int j0 = 2 * t;
  for (int i = 0; i < 64; ++i) {
    float2 wv = *(const float2*)(wrow + (size_t)i * 512 + j0);
    float f0 = xL[0][i], f1 = xL[1][i];
    a00 += f0 * wv.x; a01 += f0 * wv.y;
    a10 += f1 * wv.x; a11 += f1 * wv.y;
  }
  brL[0][j0]     = a00 >= 0.f ? a00 : 0.2f * a00;
  brL[0][j0 + 1] = a01 >= 0.f ? a01 : 0.2f * a01;
  brL[1][j0]     = a10 >= 0.f ? a10 : 0.2f * a10;
  brL[1][j0 + 1] = a11 >= 0.f ? a11 : 0.2f * a11;
  __syncthreads();
  if (t < 48) {
    int b = t / 24, rem = t % 24, d = rem / 3, c = rem % 3;
    float root = 0.f, brs = 0.f;
    for (int i = 0; i < 64; ++i) {
      root = fmaf(xL[b][i], wroot[i * 3 + c], root);
      brs  = fmaf(brL[b][d * 64 + i], wc[i * 3 + c], brs);
    }
    float v = root + brs;
    out[((size_t)b * node * DEGREE + (size_t)n * DEGREE + d) * 3 + c] = v;
  }
}

// ---------------------------------------------------------------------------
extern "C" void kernel_launch(void* const* d_in, const int* in_sizes, int n_in,
                              void* d_out, int out_size, void* d_ws, size_t ws_size,
                              hipStream_t stream) {
  const float* pts1    = (const float*)d_in[0];
  const float* d0      = (const float*)d_in[1];
  const float* w1      = (const float*)d_in[2];
  const float* b1      = (const float*)d_in[3];
  const float* dir1    = (const float*)d_in[4];
  const float* d2      = (const float*)d_in[5];
  const float* w3      = (const float*)d_in[6];
  const float* b3      = (const float*)d_in[7];
  const float* dir3    = (const float*)d_in[8];
  const float* w4      = (const float*)d_in[9];
  const float* b4      = (const float*)d_in[10];
  const float* dir4    = (const float*)d_in[11];
  const float* w5      = (const float*)d_in[12];
  const float* b5      = (const float*)d_in[13];
  const float* dir5    = (const float*)d_in[14];
  const float* root1   = (const float*)d_in[15];
  const float* branch1 = (const float*)d_in[16];
  const float* l1a     = (const float*)d_in[17];
  const float* l1b     = (const float*)d_in[18];
  const float* bias1   = (const float*)d_in[19];
  const float* root2   = (const float*)d_in[20];
  const float* branch2 = (const float*)d_in[21];
  const float* l2a     = (const float*)d_in[22];
  const float* l2b     = (const float*)d_in[23];

  // workspace layout (floats) — total ~30 MB
  float* ws = (float*)d_ws;
  size_t o = 0;
  float* sdn0 = ws + o; o += 960;
  float* sdn1 = ws + o; o += 1920;
  float* sdn2 = ws + o; o += 960;
  float* sdn3 = ws + o; o += 1920;
  float* sdn4 = ws + o; o += 1920;
  float* sdn5 = ws + o; o += 1920;
  float* wc1  = ws + o; o += 192;
  float* wc2  = ws + o; o += 192;
  float* px1  = ws + o; o += 1024;
  float* py1  = ws + o; o += 1024;
  float* pz1  = ws + o; o += 1024;
  float* px2  = ws + o; o += 8192;
  float* py2  = ws + o; o += 8192;
  float* pz2  = ws + o; o += 8192;
  int*   idxb = (int*)(ws + o); o += (size_t)2 * 4096 * KNN;
  float* ndnb = ws + o; o += (size_t)2 * 4096 * KNN * 3;
  float* fo   = ws + o; o += (size_t)2 * 4096 * 704;
  float* fmA  = ws + o; o += (size_t)2 * 4096 * 64;
  float* fmB  = ws + o; o += (size_t)2 * 4096 * 64;

  float* pc1 = (float*)d_out;                 // (2, 4096, 3)
  float* pc2 = (float*)d_out + 2 * 4096 * 3;  // (2, 32768, 3)

  prep_kernel<<<19, 256, 0, stream>>>(d0, dir1, d2, dir3, dir4, dir5,
                                      sdn0, sdn1, sdn2, sdn3, sdn4, sdn5,
                                      l1a, l1b, l2a, l2b, wc1, wc2,
                                      pts1, px1, py1, pz1);

  // ---- stage 1 (N = 512) ----
  knn_kernel<8, 4><<<2 * 512 / 4, 256, 0, stream>>>(px1, py1, pz1, 512, idxb);
  ndn_kernel<<<(2 * 512 * KNN + 255) / 256, 256, 0, stream>>>(pts1, idxb, ndnb, 512);
  op3d_kernel<<<2 * 512 * 32 / 256, 256, 0, stream>>>(ndnb, sdn0, fmA, 512);          // fm0
  fo_kernel<32><<<2 * 512 / 8, 256, 0, stream>>>(fmA, w1, b1, fo, 512);
  opnd_kernel<<<2 * 512 / 4, 256, 0, stream>>>(ndnb, idxb, fo, sdn1, fmB, 512);       // fm1
  tree_exact_kernel<<<512, 256, 0, stream>>>(fmB, root1, branch1, l1a, l1b,
                                             bias1, pc1, 512);                        // pc1

  // ---- stage 2 (N = 4096) ----
  soa2_kernel<<<32, 256, 0, stream>>>(pc1, px2, py2, pz2);
  knn_kernel<64, 4><<<2 * 4096 / 4, 256, 0, stream>>>(px2, py2, pz2, 4096, idxb);
  ndn_kernel<<<(2 * 4096 * KNN + 255) / 256, 256, 0, stream>>>(pc1, idxb, ndnb, 4096);
  op3d_kernel<<<2 * 4096 * 32 / 256, 256, 0, stream>>>(ndnb, sdn2, fmA, 4096);        // fm2
  fo_kernel<32><<<2 * 4096 / 8, 256, 0, stream>>>(fmA, w3, b3, fo, 4096);
  opnd_kernel<<<2 * 4096 / 4, 256, 0, stream>>>(ndnb, idxb, fo, sdn3, fmB, 4096);     // fm3
  fo_kernel<64><<<2 * 4096 / 8, 256, 0, stream>>>(fmB, w4, b4, fo, 4096);
  opnd_kernel<<<2 * 4096 / 4, 256, 0, stream>>>(ndnb, idxb, fo, sdn4, fmA, 4096);     // fm4
  fo_kernel<64><<<2 * 4096 / 8, 256, 0, stream>>>(fmA, w5, b5, fo, 4096);
  opnd_kernel<<<2 * 4096 / 4, 256, 0, stream>>>(ndnb, idxb, fo, sdn5, fmB, 4096);     // fm5
  tree_kernel<<<4096, 256, 0, stream>>>(fmB, root2, branch2, wc2, pc2, 4096);         // pc2
}

// Round 7
// 666.122 us; speedup vs baseline: 1.2008x; 1.2008x over previous
//
#include <hip/hip_runtime.h>
#include <hip/hip_bf16.h>
#include <stdint.h>

#define SUPPORT 10
#define KNN 20
#define DEGREE 8

// ---------------------------------------------------------------------------
// prep: normalize all 6 direction matrices (columns over axis 0, sequential
// non-FMA to match np), collapse w_l1 @ w_l2 -> 64x3 (fast pc2 path), and
// transpose pts1 to SoA (px1/py1/pz1) for coalesced kNN loads.
// grid: 19 blocks x 256
// ---------------------------------------------------------------------------
__global__ __launch_bounds__(256) void prep_kernel(
    const float* __restrict__ d0, const float* __restrict__ dir1,
    const float* __restrict__ d2, const float* __restrict__ dir3,
    const float* __restrict__ dir4, const float* __restrict__ dir5,
    float* __restrict__ sdn0, float* __restrict__ sdn1, float* __restrict__ sdn2,
    float* __restrict__ sdn3, float* __restrict__ sdn4, float* __restrict__ sdn5,
    const float* __restrict__ l1a, const float* __restrict__ l1b,
    const float* __restrict__ l2a, const float* __restrict__ l2b,
    float* __restrict__ wc1, float* __restrict__ wc2,
    const float* __restrict__ pts1,
    float* __restrict__ px1, float* __restrict__ py1, float* __restrict__ pz1) {
#pragma clang fp contract(off)
  if (blockIdx.x < 13) {
    int t = blockIdx.x * 256 + threadIdx.x;
    if (t >= 3200) return;
    const float* src; float* dst; int cols; int e;
    if (t < 320)       { src = d0;   dst = sdn0; cols = 320; e = t; }
    else if (t < 960)  { src = dir1; dst = sdn1; cols = 640; e = t - 320; }
    else if (t < 1280) { src = d2;   dst = sdn2; cols = 320; e = t - 960; }
    else if (t < 1920) { src = dir3; dst = sdn3; cols = 640; e = t - 1280; }
    else if (t < 2560) { src = dir4; dst = sdn4; cols = 640; e = t - 1920; }
    else               { src = dir5; dst = sdn5; cols = 640; e = t - 2560; }
    float a = src[e], b = src[cols + e], c = src[2 * cols + e];
    float nrm = sqrtf(a * a + b * b + c * c);
    nrm = fmaxf(nrm, 1e-12f);
    dst[e] = a / nrm; dst[cols + e] = b / nrm; dst[2 * cols + e] = c / nrm;
  } else if (blockIdx.x < 15) {
    int which = blockIdx.x - 13;          // 0 -> wc1, 1 -> wc2
    int tt = threadIdx.x;
    if (tt >= 192) return;
    const float* A  = which ? l2a : l1a;  // (64, 640)
    const float* Bm = which ? l2b : l1b;  // (640, 3)
    float* out = which ? wc2 : wc1;
    int i = tt / 3, c = tt % 3;
    float s = 0.f;
    for (int k = 0; k < 640; ++k) s = fmaf(A[i * 640 + k], Bm[k * 3 + c], s);
    out[i * 3 + c] = s;
  } else {
    int t = (blockIdx.x - 15) * 256 + threadIdx.x;  // 0..1023 over 2*512 pts
    if (t >= 1024) return;
    px1[t] = pts1[t * 3];
    py1[t] = pts1[t * 3 + 1];
    pz1[t] = pts1[t * 3 + 2];
  }
}

// ---------------------------------------------------------------------------
// soa2: transpose pc1 (2,4096,3) into SoA for stage-2 kNN.
// ---------------------------------------------------------------------------
__global__ __launch_bounds__(256) void soa2_kernel(const float* __restrict__ pc1,
                                                   float* __restrict__ px,
                                                   float* __restrict__ py,
                                                   float* __restrict__ pz) {
  int t = blockIdx.x * 256 + threadIdx.x;
  if (t >= 8192) return;
  px[t] = pc1[t * 3];
  py[t] = pc1[t * 3 + 1];
  pz[t] = pc1[t * 3 + 2];
}

// ---------------------------------------------------------------------------
// kNN (R4 known-good LDS version): one wave per query node, SoA coalesced
// loads. LDS holds flipped-float dist keys in lane-owned XOR-swizzled
// stripes. 21 rounds of wave-min selection (packed u64 = dist<<32|idx ==
// exact top_k(-dist) stable order); round 0 (self) dropped. Distance math
// sequential non-FMA = bit-identical to np einsum.
// MPER = N/64. Dyn LDS = WAVES*64*MPER*4 bytes.
// ---------------------------------------------------------------------------
template <int MPER, int WAVES>
__global__ __launch_bounds__(WAVES * 64) void knn_kernel(
    const float* __restrict__ px, const float* __restrict__ py,
    const float* __restrict__ pz, int N, int* __restrict__ idx_out) {
#pragma clang fp contract(off)
  extern __shared__ uint32_t kbuf[];
  int w = threadIdx.x >> 6, lane = threadIdx.x & 63;
  int g = blockIdx.x * WAVES + w;           // global node id in [0, 2N)
  int b = g / N, n = g % N;
  volatile uint32_t* K = kbuf + (size_t)w * 64 * MPER;
  const float* PX = px + (size_t)b * N;
  const float* PY = py + (size_t)b * N;
  const float* PZ = pz + (size_t)b * N;

  float nx = PX[n], ny = PY[n], nz = PZ[n];
  float qn = nx * nx + ny * ny + nz * nz;

  unsigned long long mymin = ~0ull;
  for (int j = 0; j < MPER; ++j) {
    int m = j * 64 + lane;
    float mx = PX[m], my = PY[m], mz = PZ[m];
    float inner = nx * mx + ny * my + nz * mz;
    float qm = mx * mx + my * my + mz * mz;
    float d = (qn - 2.0f * inner) + qm;
    uint32_t u = __float_as_uint(d);
    u ^= (u & 0x80000000u) ? 0xFFFFFFFFu : 0x80000000u;  // order-preserving flip
    K[lane * MPER + (j ^ (lane & (MPER - 1)))] = u;
    unsigned long long key = ((unsigned long long)u << 32) | (unsigned)m;
    mymin = key < mymin ? key : mymin;
  }
  for (int r = 0; r < 21; ++r) {
    unsigned long long best = mymin;
#pragma unroll
    for (int s = 1; s < 64; s <<= 1) {
      unsigned long long o = __shfl_xor(best, s, 64);
      best = o < best ? o : best;
    }
    unsigned m = (unsigned)best;
    if (r > 0 && lane == 0) idx_out[(size_t)g * KNN + (r - 1)] = (int)m;
    if (r == 20) break;
    int owner = m & 63, slot = m >> 6;
    if (lane == slot) K[owner * MPER + (slot ^ (owner & (MPER - 1)))] = 0xFFFFFFFFu;
    unsigned long long cand = ~0ull;
    if (lane < MPER) {
      uint32_t v = K[owner * MPER + (lane ^ (owner & (MPER - 1)))];
      cand = ((unsigned long long)v << 32) | (unsigned)(lane * 64 + owner);
    }
#pragma unroll
    for (int s = 1; s < 64; s <<= 1) {
      unsigned long long o = __shfl_xor(cand, s, 64);
      cand = o < cand ? o : cand;
    }
    if (lane == owner) mymin = cand;
  }
}

// ---------------------------------------------------------------------------
// ndn: normalized neighbor directions (sequential non-FMA, matches np).
// ---------------------------------------------------------------------------
__global__ __launch_bounds__(256) void ndn_kernel(const float* __restrict__ pts,
                                                  const int* __restrict__ idx,
                                                  float* __restrict__ ndn, int N) {
#pragma clang fp contract(off)
  int t = blockIdx.x * 256 + threadIdx.x;
  int total = 2 * N * KNN;
  if (t >= total) return;
  int k = t % KNN, g = t / KNN;
  int b = g / N, n = g % N;
  int m = idx[(size_t)g * KNN + k];
  const float* pb = pts + (size_t)b * N * 3;
  float dx = pb[m * 3] - pb[n * 3];
  float dy = pb[m * 3 + 1] - pb[n * 3 + 1];
  float dz = pb[m * 3 + 2] - pb[n * 3 + 2];
  float nr = sqrtf(dx * dx + dy * dy + dz * dz);
  nr = fmaxf(nr, 1e-12f);
  ndn[(size_t)t * 3] = dx / nr; ndn[(size_t)t * 3 + 1] = dy / nr; ndn[(size_t)t * 3 + 2] = dz / nr;
}

// ---------------------------------------------------------------------------
// op3d: out[g,c] = sum_s max_k relu(ndn[g,k]·sdn[:, s*32+c]); half-wave/node.
// ---------------------------------------------------------------------------
__global__ __launch_bounds__(256) void op3d_kernel(const float* __restrict__ ndn,
                                                   const float* __restrict__ sdn,
                                                   float* __restrict__ out, int N) {
#pragma clang fp contract(off)
  int c = threadIdx.x & 31;
  int g = (blockIdx.x * 256 + threadIdx.x) >> 5;
  if (g >= 2 * N) return;
  const float* nd = ndn + (size_t)g * 60;
  float sv0[SUPPORT], sv1[SUPPORT], sv2[SUPPORT], mm[SUPPORT];
#pragma unroll
  for (int s = 0; s < SUPPORT; ++s) {
    sv0[s] = sdn[s * 32 + c];
    sv1[s] = sdn[320 + s * 32 + c];
    sv2[s] = sdn[640 + s * 32 + c];
    mm[s] = 0.f;  // == max over relu'd values
  }
  for (int k = 0; k < KNN; ++k) {
    float nx = nd[k * 3], ny = nd[k * 3 + 1], nz = nd[k * 3 + 2];
#pragma unroll
    for (int s = 0; s < SUPPORT; ++s) {
      float t = nx * sv0[s] + ny * sv1[s] + nz * sv2[s];
      mm[s] = fmaxf(mm[s], t);
    }
  }
  float acc = 0.f;
#pragma unroll
  for (int s = 0; s < SUPPORT; ++s) acc += mm[s];
  out[(size_t)g * 32 + c] = acc;  // outer relu is a no-op (acc >= 0)
}

// ---------------------------------------------------------------------------
// fo = feat @ W + b: sequential-k fmaf chain per element (matches BLAS).
// Block handles 8 nodes for W reuse from L2.
// ---------------------------------------------------------------------------
template <int K>
__global__ __launch_bounds__(256) void fo_kernel(const float* __restrict__ feat,
                                                 const float* __restrict__ wmat,
                                                 const float* __restrict__ bias,
                                                 float* __restrict__ fo, int N) {
  __shared__ float fL[8 * K];
  int t = threadIdx.x;
  int gbase = blockIdx.x * 8;
  for (int i = t; i < 8 * K; i += 256) fL[i] = feat[(size_t)gbase * K + i];
  __syncthreads();
  float a0[8], a1[8], a2[8];
#pragma unroll
  for (int gg = 0; gg < 8; ++gg) { a0[gg] = 0.f; a1[gg] = 0.f; a2[gg] = 0.f; }
  bool has3 = (t < 192);
  for (int i = 0; i < K; ++i) {
    float w0 = wmat[i * 704 + t];
    float w1 = wmat[i * 704 + t + 256];
    float w2 = has3 ? wmat[i * 704 + t + 512] : 0.f;
#pragma unroll
    for (int gg = 0; gg < 8; ++gg) {
      float f = fL[gg * K + i];
      a0[gg] = fmaf(f, w0, a0[gg]);
      a1[gg] = fmaf(f, w1, a1[gg]);
      a2[gg] = fmaf(f, w2, a2[gg]);
    }
  }
  float b0 = bias[t], b1 = bias[t + 256], b2 = has3 ? bias[t + 512] : 0.f;
#pragma unroll
  for (int gg = 0; gg < 8; ++gg) {
    size_t base = (size_t)(gbase + gg) * 704;
    fo[base + t] = a0[gg] + b0;
    fo[base + t + 256] = a1[gg] + b1;
    if (has3) fo[base + t + 512] = a2[gg] + b2;
  }
}

// ---------------------------------------------------------------------------
// opnd: one wave per node, lane = output channel (64), natural block order.
// ---------------------------------------------------------------------------
__global__ __launch_bounds__(256) void opnd_kernel(const float* __restrict__ ndn,
                                                   const int* __restrict__ idx,
                                                   const float* __restrict__ fo,
                                                   const float* __restrict__ sdn,
                                                   float* __restrict__ fm, int N) {
#pragma clang fp contract(off)
  __shared__ float ndL[4][64];
  __shared__ int offL[4][24];
  int w = threadIdx.x >> 6, lane = threadIdx.x & 63;
  int g = blockIdx.x * 4 + w;
  if (lane < 60) ndL[w][lane] = ndn[(size_t)g * 60 + lane];
  if (lane < KNN) offL[w][lane] = ((g / N) * N + idx[(size_t)g * KNN + lane]) * 704 + 64;
  __syncthreads();
  const float* ndw = ndL[w];
  const int* offw = offL[w];
  float sv0[SUPPORT], sv1[SUPPORT], sv2[SUPPORT], mm[SUPPORT];
#pragma unroll
  for (int s = 0; s < SUPPORT; ++s) {
    sv0[s] = sdn[s * 64 + lane];
    sv1[s] = sdn[640 + s * 64 + lane];
    sv2[s] = sdn[1280 + s * 64 + lane];
    mm[s] = -__builtin_inff();
  }
  for (int k = 0; k < KNN; ++k) {
    float nx = ndw[k * 3], ny = ndw[k * 3 + 1], nz = ndw[k * 3 + 2];
    int off = offw[k];
#pragma unroll
    for (int s = 0; s < SUPPORT; ++s) {
      float t = fmaxf(nx * sv0[s] + ny * sv1[s] + nz * sv2[s], 0.f);
      float f = fo[(size_t)off + s * 64 + lane];
      mm[s] = fmaxf(mm[s], t * f);
    }
  }
  float acc = 0.f;
#pragma unroll
  for (int s = 0; s < SUPPORT; ++s) acc += mm[s];
  float fc = fo[(size_t)g * 704 + lane];
  float v = fc + acc;
  fm[(size_t)g * 64 + lane] = fmaxf(v, 0.f);
}

// ---------------------------------------------------------------------------
// tree_gcn EXACT (pc1 only): mirrors np op-by-op; bit-identical element
// arithmetic (pc1 feeds stage-2 kNN so this must track np).
// ---------------------------------------------------------------------------
__global__ __launch_bounds__(256) void tree_exact_kernel(
    const float* __restrict__ x, const float* __restrict__ wroot,
    const float* __restrict__ wb, const float* __restrict__ l1,
    const float* __restrict__ l2, const float* __restrict__ bias,
    float* __restrict__ out, int node) {
#pragma clang fp contract(off)
  __shared__ float xL[2][64];
  __shared__ float brL[2][512];
  __shared__ float tL[16][640];
  __shared__ float rootv[2][3];
  int n = blockIdx.x, t = threadIdx.x;
  if (t < 128) xL[t >> 6][t & 63] = x[(size_t)(t >> 6) * node * 64 + (size_t)n * 64 + (t & 63)];
  __syncthreads();
  {
    const float* wrow = wb + (size_t)n * 64 * 512;
    int j0 = 2 * t;
    float a00 = 0.f, a01 = 0.f, a10 = 0.f, a11 = 0.f;
    for (int i = 0; i < 64; ++i) {
      float w0 = wrow[(size_t)i * 512 + j0];
      float w1 = wrow[(size_t)i * 512 + j0 + 1];
      float f0 = xL[0][i], f1 = xL[1][i];
      a00 = a00 + f0 * w0; a01 = a01 + f0 * w1;
      a10 = a10 + f1 * w0; a11 = a11 + f1 * w1;
    }
    brL[0][j0]     = a00 >= 0.f ? a00 : 0.2f * a00;
    brL[0][j0 + 1] = a01 >= 0.f ? a01 : 0.2f * a01;
    brL[1][j0]     = a10 >= 0.f ? a10 : 0.2f * a10;
    brL[1][j0 + 1] = a11 >= 0.f ? a11 : 0.2f * a11;
  }
  if (t < 6) {
    int b = t / 3, c = t % 3;
    float r = 0.f;
    for (int i = 0; i < 64; ++i) r = fmaf(xL[b][i], wroot[i * 3 + c], r);
    rootv[b][c] = r;
  }
  __syncthreads();
#pragma unroll 4
  for (int u = 0; u < 40; ++u) {        // 16*640 / 256
    int e = u * 256 + t;
    int p = e / 640, j = e % 640;       // p: b = p>>3, d = p&7
    const float* brow = brL[p >> 3] + (p & 7) * 64;
    float acc = 0.f;
    for (int i = 0; i < 64; ++i)
      acc = fmaf(brow[i], l1[i * 640 + j], acc);
    tL[p][j] = acc;
  }
  __syncthreads();
  if (t < 48) {
    int p = t / 3, c = t % 3, b = p >> 3, d = p & 7;
    float s = 0.f;
    for (int j = 0; j < 640; ++j) s = fmaf(tL[p][j], l2[j * 3 + c], s);
    float v = rootv[b][c] + s;
    v = v + bias[d * 3 + c];
    v = v >= 0.f ? v : 0.2f * v;
    out[((size_t)b * node * DEGREE + (size_t)n * DEGREE + d) * 3 + c] = v;
  }
}

// ---------------------------------------------------------------------------
// tree_gcn FAST (pc2): collapsed w_l1@w_l2, HBM-bound on the w_branch stream.
// 2 nodes/block, float4 weight loads: 16 B/lane x 64 lanes = 1 KB per load
// instruction (coalescing sweet spot) — halves VMEM instr count vs float2.
// Per-output accumulation order over i unchanged -> bit-identical pc2.
// ---------------------------------------------------------------------------
__global__ __launch_bounds__(256) void tree_kernel(const float* __restrict__ x,
                                                   const float* __restrict__ wroot,
                                                   const float* __restrict__ wb,
                                                   const float* __restrict__ wc,
                                                   float* __restrict__ out,
                                                   int node) {
  __shared__ float xL[2][2][64];     // [node-sub][batch][i]
  __shared__ float brL[2][2][512];   // [node-sub][batch][j]
  int t = threadIdx.x;
  int n0 = blockIdx.x * 2;
  if (t < 256) {
    int which = t >> 6;              // 0..3: nsub = which>>1, batch = which&1
    int ns = which >> 1, bb = which & 1;
    xL[ns][bb][t & 63] = x[(size_t)bb * node * 64 + (size_t)(n0 + ns) * 64 + (t & 63)];
  }
  __syncthreads();
  int ns = t >> 7;                   // node sub-index (0..1)
  int j0 = (t & 127) * 4;            // 4 consecutive cols of 512
  const float* wrow = wb + (size_t)(n0 + ns) * 64 * 512;
  float a0x = 0.f, a0y = 0.f, a0z = 0.f, a0w = 0.f;
  float a1x = 0.f, a1y = 0.f, a1z = 0.f, a1w = 0.f;
  for (int i = 0; i < 64; ++i) {
    float4 wv = *(const float4*)(wrow + (size_t)i * 512 + j0);
    float f0 = xL[ns][0][i], f1 = xL[ns][1][i];
    a0x += f0 * wv.x; a0y += f0 * wv.y; a0z += f0 * wv.z; a0w += f0 * wv.w;
    a1x += f1 * wv.x; a1y += f1 * wv.y; a1z += f1 * wv.z; a1w += f1 * wv.w;
  }
  brL[ns][0][j0]     = a0x >= 0.f ? a0x : 0.2f * a0x;
  brL[ns][0][j0 + 1] = a0y >= 0.f ? a0y : 0.2f * a0y;
  brL[ns][0][j0 + 2] = a0z >= 0.f ? a0z : 0.2f * a0z;
  brL[ns][0][j0 + 3] = a0w >= 0.f ? a0w : 0.2f * a0w;
  brL[ns][1][j0]     = a1x >= 0.f ? a1x : 0.2f * a1x;
  brL[ns][1][j0 + 1] = a1y >= 0.f ? a1y : 0.2f * a1y;
  brL[ns][1][j0 + 2] = a1z >= 0.f ? a1z : 0.2f * a1z;
  brL[ns][1][j0 + 3] = a1w >= 0.f ? a1w : 0.2f * a1w;
  __syncthreads();
  if (t < 96) {
    int nsub = t / 48, rem = t % 48;
    int b = rem / 24, r2 = rem % 24, d = r2 / 3, c = r2 % 3;
    float root = 0.f, brs = 0.f;
    for (int i = 0; i < 64; ++i) {
      root = fmaf(xL[nsub][b][i], wroot[i * 3 + c], root);
      brs  = fmaf(brL[nsub][b][d * 64 + i], wc[i * 3 + c], brs);
    }
    float v = root + brs;
    out[((size_t)b * node * DEGREE + (size_t)(n0 + nsub) * DEGREE + d) * 3 + c] = v;
  }
}

// ---------------------------------------------------------------------------
extern "C" void kernel_launch(void* const* d_in, const int* in_sizes, int n_in,
                              void* d_out, int out_size, void* d_ws, size_t ws_size,
                              hipStream_t stream) {
  const float* pts1    = (const float*)d_in[0];
  const float* d0      = (const float*)d_in[1];
  const float* w1      = (const float*)d_in[2];
  const float* b1      = (const float*)d_in[3];
  const float* dir1    = (const float*)d_in[4];
  const float* d2      = (const float*)d_in[5];
  const float* w3      = (const float*)d_in[6];
  const float* b3      = (const float*)d_in[7];
  const float* dir3    = (const float*)d_in[8];
  const float* w4      = (const float*)d_in[9];
  const float* b4      = (const float*)d_in[10];
  const float* dir4    = (const float*)d_in[11];
  const float* w5      = (const float*)d_in[12];
  const float* b5      = (const float*)d_in[13];
  const float* dir5    = (const float*)d_in[14];
  const float* root1   = (const float*)d_in[15];
  const float* branch1 = (const float*)d_in[16];
  const float* l1a     = (const float*)d_in[17];
  const float* l1b     = (const float*)d_in[18];
  const float* bias1   = (const float*)d_in[19];
  const float* root2   = (const float*)d_in[20];
  const float* branch2 = (const float*)d_in[21];
  const float* l2a     = (const float*)d_in[22];
  const float* l2b     = (const float*)d_in[23];

  // workspace layout (floats) — total ~30 MB
  float* ws = (float*)d_ws;
  size_t o = 0;
  float* sdn0 = ws + o; o += 960;
  float* sdn1 = ws + o; o += 1920;
  float* sdn2 = ws + o; o += 960;
  float* sdn3 = ws + o; o += 1920;
  float* sdn4 = ws + o; o += 1920;
  float* sdn5 = ws + o; o += 1920;
  float* wc1  = ws + o; o += 192;
  float* wc2  = ws + o; o += 192;
  float* px1  = ws + o; o += 1024;
  float* py1  = ws + o; o += 1024;
  float* pz1  = ws + o; o += 1024;
  float* px2  = ws + o; o += 8192;
  float* py2  = ws + o; o += 8192;
  float* pz2  = ws + o; o += 8192;
  int*   idxb = (int*)(ws + o); o += (size_t)2 * 4096 * KNN;
  float* ndnb = ws + o; o += (size_t)2 * 4096 * KNN * 3;
  float* fo   = ws + o; o += (size_t)2 * 4096 * 704;
  float* fmA  = ws + o; o += (size_t)2 * 4096 * 64;
  float* fmB  = ws + o; o += (size_t)2 * 4096 * 64;

  float* pc1 = (float*)d_out;                 // (2, 4096, 3)
  float* pc2 = (float*)d_out + 2 * 4096 * 3;  // (2, 32768, 3)

  prep_kernel<<<19, 256, 0, stream>>>(d0, dir1, d2, dir3, dir4, dir5,
                                      sdn0, sdn1, sdn2, sdn3, sdn4, sdn5,
                                      l1a, l1b, l2a, l2b, wc1, wc2,
                                      pts1, px1, py1, pz1);

  // ---- stage 1 (N = 512) ----
  knn_kernel<8, 4><<<2 * 512 / 4, 256, 4 * 64 * 8 * 4, stream>>>(px1, py1, pz1, 512, idxb);
  ndn_kernel<<<(2 * 512 * KNN + 255) / 256, 256, 0, stream>>>(pts1, idxb, ndnb, 512);
  op3d_kernel<<<2 * 512 * 32 / 256, 256, 0, stream>>>(ndnb, sdn0, fmA, 512);          // fm0
  fo_kernel<32><<<2 * 512 / 8, 256, 0, stream>>>(fmA, w1, b1, fo, 512);
  opnd_kernel<<<2 * 512 / 4, 256, 0, stream>>>(ndnb, idxb, fo, sdn1, fmB, 512);       // fm1
  tree_exact_kernel<<<512, 256, 0, stream>>>(fmB, root1, branch1, l1a, l1b,
                                             bias1, pc1, 512);                        // pc1

  // ---- stage 2 (N = 4096) ----
  soa2_kernel<<<32, 256, 0, stream>>>(pc1, px2, py2, pz2);
  knn_kernel<64, 2><<<2 * 4096 / 2, 128, 2 * 64 * 64 * 4, stream>>>(px2, py2, pz2, 4096, idxb);
  ndn_kernel<<<(2 * 4096 * KNN + 255) / 256, 256, 0, stream>>>(pc1, idxb, ndnb, 4096);
  op3d_kernel<<<2 * 4096 * 32 / 256, 256, 0, stream>>>(ndnb, sdn2, fmA, 4096);        // fm2
  fo_kernel<32><<<2 * 4096 / 8, 256, 0, stream>>>(fmA, w3, b3, fo, 4096);
  opnd_kernel<<<2 * 4096 / 4, 256, 0, stream>>>(ndnb, idxb, fo, sdn3, fmB, 4096);     // fm3
  fo_kernel<64><<<2 * 4096 / 8, 256, 0, stream>>>(fmB, w4, b4, fo, 4096);
  opnd_kernel<<<2 * 4096 / 4, 256, 0, stream>>>(ndnb, idxb, fo, sdn4, fmA, 4096);     // fm4
  fo_kernel<64><<<2 * 4096 / 8, 256, 0, stream>>>(fmA, w5, b5, fo, 4096);
  opnd_kernel<<<2 * 4096 / 4, 256, 0, stream>>>(ndnb, idxb, fo, sdn5, fmB, 4096);     // fm5
  tree_kernel<<<4096 / 2, 256, 0, stream>>>(fmB, root2, branch2, wc2, pc2, 4096);     // pc2
}

// Round 8
// 655.265 us; speedup vs baseline: 1.2207x; 1.0166x over previous
//
#include <hip/hip_runtime.h>
#include <hip/hip_bf16.h>
#include <stdint.h>

#define SUPPORT 10
#define KNN 20
#define DEGREE 8

// ---------------------------------------------------------------------------
// prep: normalize all 6 direction matrices (columns over axis 0, sequential
// non-FMA to match np), collapse w_l1 @ w_l2 -> 64x3 (fast pc2 path), and
// transpose pts1 to SoA (px1/py1/pz1) for coalesced kNN loads.
// grid: 19 blocks x 256
// ---------------------------------------------------------------------------
__global__ __launch_bounds__(256) void prep_kernel(
    const float* __restrict__ d0, const float* __restrict__ dir1,
    const float* __restrict__ d2, const float* __restrict__ dir3,
    const float* __restrict__ dir4, const float* __restrict__ dir5,
    float* __restrict__ sdn0, float* __restrict__ sdn1, float* __restrict__ sdn2,
    float* __restrict__ sdn3, float* __restrict__ sdn4, float* __restrict__ sdn5,
    const float* __restrict__ l1a, const float* __restrict__ l1b,
    const float* __restrict__ l2a, const float* __restrict__ l2b,
    float* __restrict__ wc1, float* __restrict__ wc2,
    const float* __restrict__ pts1,
    float* __restrict__ px1, float* __restrict__ py1, float* __restrict__ pz1) {
#pragma clang fp contract(off)
  if (blockIdx.x < 13) {
    int t = blockIdx.x * 256 + threadIdx.x;
    if (t >= 3200) return;
    const float* src; float* dst; int cols; int e;
    if (t < 320)       { src = d0;   dst = sdn0; cols = 320; e = t; }
    else if (t < 960)  { src = dir1; dst = sdn1; cols = 640; e = t - 320; }
    else if (t < 1280) { src = d2;   dst = sdn2; cols = 320; e = t - 960; }
    else if (t < 1920) { src = dir3; dst = sdn3; cols = 640; e = t - 1280; }
    else if (t < 2560) { src = dir4; dst = sdn4; cols = 640; e = t - 1920; }
    else               { src = dir5; dst = sdn5; cols = 640; e = t - 2560; }
    float a = src[e], b = src[cols + e], c = src[2 * cols + e];
    float nrm = sqrtf(a * a + b * b + c * c);
    nrm = fmaxf(nrm, 1e-12f);
    dst[e] = a / nrm; dst[cols + e] = b / nrm; dst[2 * cols + e] = c / nrm;
  } else if (blockIdx.x < 15) {
    int which = blockIdx.x - 13;          // 0 -> wc1, 1 -> wc2
    int tt = threadIdx.x;
    if (tt >= 192) return;
    const float* A  = which ? l2a : l1a;  // (64, 640)
    const float* Bm = which ? l2b : l1b;  // (640, 3)
    float* out = which ? wc2 : wc1;
    int i = tt / 3, c = tt % 3;
    float s = 0.f;
    for (int k = 0; k < 640; ++k) s = fmaf(A[i * 640 + k], Bm[k * 3 + c], s);
    out[i * 3 + c] = s;
  } else {
    int t = (blockIdx.x - 15) * 256 + threadIdx.x;  // 0..1023 over 2*512 pts
    if (t >= 1024) return;
    px1[t] = pts1[t * 3];
    py1[t] = pts1[t * 3 + 1];
    pz1[t] = pts1[t * 3 + 2];
  }
}

// ---------------------------------------------------------------------------
// soa2: transpose pc1 (2,4096,3) into SoA for stage-2 kNN.
// ---------------------------------------------------------------------------
__global__ __launch_bounds__(256) void soa2_kernel(const float* __restrict__ pc1,
                                                   float* __restrict__ px,
                                                   float* __restrict__ py,
                                                   float* __restrict__ pz) {
  int t = blockIdx.x * 256 + threadIdx.x;
  if (t >= 8192) return;
  px[t] = pc1[t * 3];
  py[t] = pc1[t * 3 + 1];
  pz[t] = pc1[t * 3 + 2];
}

// ---------------------------------------------------------------------------
// kNN (known-good LDS version): one wave per query node, SoA coalesced
// loads. LDS holds flipped-float dist keys in lane-owned XOR-swizzled
// stripes. 21 rounds of wave-min selection (packed u64 = dist<<32|idx ==
// exact top_k(-dist) stable order); round 0 (self) dropped. Distance math
// sequential non-FMA = bit-identical to np einsum.
// MPER = N/64. Dyn LDS = WAVES*64*MPER*4 bytes.
// ---------------------------------------------------------------------------
template <int MPER, int WAVES>
__global__ __launch_bounds__(WAVES * 64) void knn_kernel(
    const float* __restrict__ px, const float* __restrict__ py,
    const float* __restrict__ pz, int N, int* __restrict__ idx_out) {
#pragma clang fp contract(off)
  extern __shared__ uint32_t kbuf[];
  int w = threadIdx.x >> 6, lane = threadIdx.x & 63;
  int g = blockIdx.x * WAVES + w;           // global node id in [0, 2N)
  int b = g / N, n = g % N;
  volatile uint32_t* K = kbuf + (size_t)w * 64 * MPER;
  const float* PX = px + (size_t)b * N;
  const float* PY = py + (size_t)b * N;
  const float* PZ = pz + (size_t)b * N;

  float nx = PX[n], ny = PY[n], nz = PZ[n];
  float qn = nx * nx + ny * ny + nz * nz;

  unsigned long long mymin = ~0ull;
  for (int j = 0; j < MPER; ++j) {
    int m = j * 64 + lane;
    float mx = PX[m], my = PY[m], mz = PZ[m];
    float inner = nx * mx + ny * my + nz * mz;
    float qm = mx * mx + my * my + mz * mz;
    float d = (qn - 2.0f * inner) + qm;
    uint32_t u = __float_as_uint(d);
    u ^= (u & 0x80000000u) ? 0xFFFFFFFFu : 0x80000000u;  // order-preserving flip
    K[lane * MPER + (j ^ (lane & (MPER - 1)))] = u;
    unsigned long long key = ((unsigned long long)u << 32) | (unsigned)m;
    mymin = key < mymin ? key : mymin;
  }
  for (int r = 0; r < 21; ++r) {
    unsigned long long best = mymin;
#pragma unroll
    for (int s = 1; s < 64; s <<= 1) {
      unsigned long long o = __shfl_xor(best, s, 64);
      best = o < best ? o : best;
    }
    unsigned m = (unsigned)best;
    if (r > 0 && lane == 0) idx_out[(size_t)g * KNN + (r - 1)] = (int)m;
    if (r == 20) break;
    int owner = m & 63, slot = m >> 6;
    if (lane == slot) K[owner * MPER + (slot ^ (owner & (MPER - 1)))] = 0xFFFFFFFFu;
    unsigned long long cand = ~0ull;
    if (lane < MPER) {
      uint32_t v = K[owner * MPER + (lane ^ (owner & (MPER - 1)))];
      cand = ((unsigned long long)v << 32) | (unsigned)(lane * 64 + owner);
    }
#pragma unroll
    for (int s = 1; s < 64; s <<= 1) {
      unsigned long long o = __shfl_xor(cand, s, 64);
      cand = o < cand ? o : cand;
    }
    if (lane == owner) mymin = cand;
  }
}

// ---------------------------------------------------------------------------
// ndn: normalized neighbor directions (sequential non-FMA, matches np).
// ---------------------------------------------------------------------------
__global__ __launch_bounds__(256) void ndn_kernel(const float* __restrict__ pts,
                                                  const int* __restrict__ idx,
                                                  float* __restrict__ ndn, int N) {
#pragma clang fp contract(off)
  int t = blockIdx.x * 256 + threadIdx.x;
  int total = 2 * N * KNN;
  if (t >= total) return;
  int k = t % KNN, g = t / KNN;
  int b = g / N, n = g % N;
  int m = idx[(size_t)g * KNN + k];
  const float* pb = pts + (size_t)b * N * 3;
  float dx = pb[m * 3] - pb[n * 3];
  float dy = pb[m * 3 + 1] - pb[n * 3 + 1];
  float dz = pb[m * 3 + 2] - pb[n * 3 + 2];
  float nr = sqrtf(dx * dx + dy * dy + dz * dz);
  nr = fmaxf(nr, 1e-12f);
  ndn[(size_t)t * 3] = dx / nr; ndn[(size_t)t * 3 + 1] = dy / nr; ndn[(size_t)t * 3 + 2] = dz / nr;
}

// ---------------------------------------------------------------------------
// op3d: out[g,c] = sum_s max_k relu(ndn[g,k]·sdn[:, s*32+c]); half-wave/node.
// ---------------------------------------------------------------------------
__global__ __launch_bounds__(256) void op3d_kernel(const float* __restrict__ ndn,
                                                   const float* __restrict__ sdn,
                                                   float* __restrict__ out, int N) {
#pragma clang fp contract(off)
  int c = threadIdx.x & 31;
  int g = (blockIdx.x * 256 + threadIdx.x) >> 5;
  if (g >= 2 * N) return;
  const float* nd = ndn + (size_t)g * 60;
  float sv0[SUPPORT], sv1[SUPPORT], sv2[SUPPORT], mm[SUPPORT];
#pragma unroll
  for (int s = 0; s < SUPPORT; ++s) {
    sv0[s] = sdn[s * 32 + c];
    sv1[s] = sdn[320 + s * 32 + c];
    sv2[s] = sdn[640 + s * 32 + c];
    mm[s] = 0.f;  // == max over relu'd values
  }
  for (int k = 0; k < KNN; ++k) {
    float nx = nd[k * 3], ny = nd[k * 3 + 1], nz = nd[k * 3 + 2];
#pragma unroll
    for (int s = 0; s < SUPPORT; ++s) {
      float t = nx * sv0[s] + ny * sv1[s] + nz * sv2[s];
      mm[s] = fmaxf(mm[s], t);
    }
  }
  float acc = 0.f;
#pragma unroll
  for (int s = 0; s < SUPPORT; ++s) acc += mm[s];
  out[(size_t)g * 32 + c] = acc;  // outer relu is a no-op (acc >= 0)
}

// ---------------------------------------------------------------------------
// fo = feat @ W + b: sequential-k fmaf chain per element (matches BLAS).
// Block handles 8 nodes for W reuse from L2.
// ---------------------------------------------------------------------------
template <int K>
__global__ __launch_bounds__(256) void fo_kernel(const float* __restrict__ feat,
                                                 const float* __restrict__ wmat,
                                                 const float* __restrict__ bias,
                                                 float* __restrict__ fo, int N) {
  __shared__ float fL[8 * K];
  int t = threadIdx.x;
  int gbase = blockIdx.x * 8;
  for (int i = t; i < 8 * K; i += 256) fL[i] = feat[(size_t)gbase * K + i];
  __syncthreads();
  float a0[8], a1[8], a2[8];
#pragma unroll
  for (int gg = 0; gg < 8; ++gg) { a0[gg] = 0.f; a1[gg] = 0.f; a2[gg] = 0.f; }
  bool has3 = (t < 192);
  for (int i = 0; i < K; ++i) {
    float w0 = wmat[i * 704 + t];
    float w1 = wmat[i * 704 + t + 256];
    float w2 = has3 ? wmat[i * 704 + t + 512] : 0.f;
#pragma unroll
    for (int gg = 0; gg < 8; ++gg) {
      float f = fL[gg * K + i];
      a0[gg] = fmaf(f, w0, a0[gg]);
      a1[gg] = fmaf(f, w1, a1[gg]);
      a2[gg] = fmaf(f, w2, a2[gg]);
    }
  }
  float b0 = bias[t], b1 = bias[t + 256], b2 = has3 ? bias[t + 512] : 0.f;
#pragma unroll
  for (int gg = 0; gg < 8; ++gg) {
    size_t base = (size_t)(gbase + gg) * 704;
    fo[base + t] = a0[gg] + b0;
    fo[base + t + 256] = a1[gg] + b1;
    if (has3) fo[base + t + 512] = a2[gg] + b2;
  }
}

// ---------------------------------------------------------------------------
// opnd: one wave per node, lane = output channel (64). Chunked inverse-XCD
// block swizzle: with round-robin block->XCD dispatch, XCD x processes a
// contiguous ~nb/8-block chunk of nodes, so its fo gather window (~3 MB for
// 1024 tree-ordered nodes) stays L2-resident instead of thrashing L3.
// Mapping-only change: outputs bit-identical.
// ---------------------------------------------------------------------------
__global__ __launch_bounds__(256) void opnd_kernel(const float* __restrict__ ndn,
                                                   const int* __restrict__ idx,
                                                   const float* __restrict__ fo,
                                                   const float* __restrict__ sdn,
                                                   float* __restrict__ fm, int N) {
#pragma clang fp contract(off)
  __shared__ float ndL[4][64];
  __shared__ int offL[4][24];
  int nb = gridDim.x;                                   // multiple of 8
  int lb = (blockIdx.x & 7) * (nb >> 3) + (blockIdx.x >> 3);
  int w = threadIdx.x >> 6, lane = threadIdx.x & 63;
  int g = lb * 4 + w;
  if (lane < 60) ndL[w][lane] = ndn[(size_t)g * 60 + lane];
  if (lane < KNN) offL[w][lane] = ((g / N) * N + idx[(size_t)g * KNN + lane]) * 704 + 64;
  __syncthreads();
  const float* ndw = ndL[w];
  const int* offw = offL[w];
  float sv0[SUPPORT], sv1[SUPPORT], sv2[SUPPORT], mm[SUPPORT];
#pragma unroll
  for (int s = 0; s < SUPPORT; ++s) {
    sv0[s] = sdn[s * 64 + lane];
    sv1[s] = sdn[640 + s * 64 + lane];
    sv2[s] = sdn[1280 + s * 64 + lane];
    mm[s] = -__builtin_inff();
  }
  for (int k = 0; k < KNN; ++k) {
    float nx = ndw[k * 3], ny = ndw[k * 3 + 1], nz = ndw[k * 3 + 2];
    int off = offw[k];
#pragma unroll
    for (int s = 0; s < SUPPORT; ++s) {
      float t = fmaxf(nx * sv0[s] + ny * sv1[s] + nz * sv2[s], 0.f);
      float f = fo[(size_t)off + s * 64 + lane];
      mm[s] = fmaxf(mm[s], t * f);
    }
  }
  float acc = 0.f;
#pragma unroll
  for (int s = 0; s < SUPPORT; ++s) acc += mm[s];
  float fc = fo[(size_t)g * 704 + lane];
  float v = fc + acc;
  fm[(size_t)g * 64 + lane] = fmaxf(v, 0.f);
}

// ---------------------------------------------------------------------------
// tree_gcn EXACT (pc1 only): mirrors np op-by-op; bit-identical element
// arithmetic (pc1 feeds stage-2 kNN so this must track np).
// ---------------------------------------------------------------------------
__global__ __launch_bounds__(256) void tree_exact_kernel(
    const float* __restrict__ x, const float* __restrict__ wroot,
    const float* __restrict__ wb, const float* __restrict__ l1,
    const float* __restrict__ l2, const float* __restrict__ bias,
    float* __restrict__ out, int node) {
#pragma clang fp contract(off)
  __shared__ float xL[2][64];
  __shared__ float brL[2][512];
  __shared__ float tL[16][640];
  __shared__ float rootv[2][3];
  int n = blockIdx.x, t = threadIdx.x;
  if (t < 128) xL[t >> 6][t & 63] = x[(size_t)(t >> 6) * node * 64 + (size_t)n * 64 + (t & 63)];
  __syncthreads();
  {
    const float* wrow = wb + (size_t)n * 64 * 512;
    int j0 = 2 * t;
    float a00 = 0.f, a01 = 0.f, a10 = 0.f, a11 = 0.f;
    for (int i = 0; i < 64; ++i) {
      float w0 = wrow[(size_t)i * 512 + j0];
      float w1 = wrow[(size_t)i * 512 + j0 + 1];
      float f0 = xL[0][i], f1 = xL[1][i];
      a00 = a00 + f0 * w0; a01 = a01 + f0 * w1;
      a10 = a10 + f1 * w0; a11 = a11 + f1 * w1;
    }
    brL[0][j0]     = a00 >= 0.f ? a00 : 0.2f * a00;
    brL[0][j0 + 1] = a01 >= 0.f ? a01 : 0.2f * a01;
    brL[1][j0]     = a10 >= 0.f ? a10 : 0.2f * a10;
    brL[1][j0 + 1] = a11 >= 0.f ? a11 : 0.2f * a11;
  }
  if (t < 6) {
    int b = t / 3, c = t % 3;
    float r = 0.f;
    for (int i = 0; i < 64; ++i) r = fmaf(xL[b][i], wroot[i * 3 + c], r);
    rootv[b][c] = r;
  }
  __syncthreads();
#pragma unroll 4
  for (int u = 0; u < 40; ++u) {        // 16*640 / 256
    int e = u * 256 + t;
    int p = e / 640, j = e % 640;       // p: b = p>>3, d = p&7
    const float* brow = brL[p >> 3] + (p & 7) * 64;
    float acc = 0.f;
    for (int i = 0; i < 64; ++i)
      acc = fmaf(brow[i], l1[i * 640 + j], acc);
    tL[p][j] = acc;
  }
  __syncthreads();
  if (t < 48) {
    int p = t / 3, c = t % 3, b = p >> 3, d = p & 7;
    float s = 0.f;
    for (int j = 0; j < 640; ++j) s = fmaf(tL[p][j], l2[j * 3 + c], s);
    float v = rootv[b][c] + s;
    v = v + bias[d * 3 + c];
    v = v >= 0.f ? v : 0.2f * v;
    out[((size_t)b * node * DEGREE + (size_t)n * DEGREE + d) * 3 + c] = v;
  }
}

// ---------------------------------------------------------------------------
// tree_gcn FAST (pc2): collapsed w_l1@w_l2, HBM-bound on the w_branch stream.
// 2 nodes/block, float4 weight loads (1 KB/wave/instr). Accumulation order
// over i unchanged -> bit-identical pc2.
// ---------------------------------------------------------------------------
__global__ __launch_bounds__(256) void tree_kernel(const float* __restrict__ x,
                                                   const float* __restrict__ wroot,
                                                   const float* __restrict__ wb,
                                                   const float* __restrict__ wc,
                                                   float* __restrict__ out,
                                                   int node) {
  __shared__ float xL[2][2][64];     // [node-sub][batch][i]
  __shared__ float brL[2][2][512];   // [node-sub][batch][j]
  int t = threadIdx.x;
  int n0 = blockIdx.x * 2;
  if (t < 256) {
    int which = t >> 6;              // 0..3: nsub = which>>1, batch = which&1
    int ns = which >> 1, bb = which & 1;
    xL[ns][bb][t & 63] = x[(size_t)bb * node * 64 + (size_t)(n0 + ns) * 64 + (t & 63)];
  }
  __syncthreads();
  int ns = t >> 7;                   // node sub-index (0..1)
  int j0 = (t & 127) * 4;            // 4 consecutive cols of 512
  const float* wrow = wb + (size_t)(n0 + ns) * 64 * 512;
  float a0x = 0.f, a0y = 0.f, a0z = 0.f, a0w = 0.f;
  float a1x = 0.f, a1y = 0.f, a1z = 0.f, a1w = 0.f;
  for (int i = 0; i < 64; ++i) {
    float4 wv = *(const float4*)(wrow + (size_t)i * 512 + j0);
    float f0 = xL[ns][0][i], f1 = xL[ns][1][i];
    a0x += f0 * wv.x; a0y += f0 * wv.y; a0z += f0 * wv.z; a0w += f0 * wv.w;
    a1x += f1 * wv.x; a1y += f1 * wv.y; a1z += f1 * wv.z; a1w += f1 * wv.w;
  }
  brL[ns][0][j0]     = a0x >= 0.f ? a0x : 0.2f * a0x;
  brL[ns][0][j0 + 1] = a0y >= 0.f ? a0y : 0.2f * a0y;
  brL[ns][0][j0 + 2] = a0z >= 0.f ? a0z : 0.2f * a0z;
  brL[ns][0][j0 + 3] = a0w >= 0.f ? a0w : 0.2f * a0w;
  brL[ns][1][j0]     = a1x >= 0.f ? a1x : 0.2f * a1x;
  brL[ns][1][j0 + 1] = a1y >= 0.f ? a1y : 0.2f * a1y;
  brL[ns][1][j0 + 2] = a1z >= 0.f ? a1z : 0.2f * a1z;
  brL[ns][1][j0 + 3] = a1w >= 0.f ? a1w : 0.2f * a1w;
  __syncthreads();
  if (t < 96) {
    int nsub = t / 48, rem = t % 48;
    int b = rem / 24, r2 = rem % 24, d = r2 / 3, c = r2 % 3;
    float root = 0.f, brs = 0.f;
    for (int i = 0; i < 64; ++i) {
      root = fmaf(xL[nsub][b][i], wroot[i * 3 + c], root);
      brs  = fmaf(brL[nsub][b][d * 64 + i], wc[i * 3 + c], brs);
    }
    float v = root + brs;
    out[((size_t)b * node * DEGREE + (size_t)(n0 + nsub) * DEGREE + d) * 3 + c] = v;
  }
}

// ---------------------------------------------------------------------------
extern "C" void kernel_launch(void* const* d_in, const int* in_sizes, int n_in,
                              void* d_out, int out_size, void* d_ws, size_t ws_size,
                              hipStream_t stream) {
  const float* pts1    = (const float*)d_in[0];
  const float* d0      = (const float*)d_in[1];
  const float* w1      = (const float*)d_in[2];
  const float* b1      = (const float*)d_in[3];
  const float* dir1    = (const float*)d_in[4];
  const float* d2      = (const float*)d_in[5];
  const float* w3      = (const float*)d_in[6];
  const float* b3      = (const float*)d_in[7];
  const float* dir3    = (const float*)d_in[8];
  const float* w4      = (const float*)d_in[9];
  const float* b4      = (const float*)d_in[10];
  const float* dir4    = (const float*)d_in[11];
  const float* w5      = (const float*)d_in[12];
  const float* b5      = (const float*)d_in[13];
  const float* dir5    = (const float*)d_in[14];
  const float* root1   = (const float*)d_in[15];
  const float* branch1 = (const float*)d_in[16];
  const float* l1a     = (const float*)d_in[17];
  const float* l1b     = (const float*)d_in[18];
  const float* bias1   = (const float*)d_in[19];
  const float* root2   = (const float*)d_in[20];
  const float* branch2 = (const float*)d_in[21];
  const float* l2a     = (const float*)d_in[22];
  const float* l2b     = (const float*)d_in[23];

  // workspace layout (floats) — total ~30 MB
  float* ws = (float*)d_ws;
  size_t o = 0;
  float* sdn0 = ws + o; o += 960;
  float* sdn1 = ws + o; o += 1920;
  float* sdn2 = ws + o; o += 960;
  float* sdn3 = ws + o; o += 1920;
  float* sdn4 = ws + o; o += 1920;
  float* sdn5 = ws + o; o += 1920;
  float* wc1  = ws + o; o += 192;
  float* wc2  = ws + o; o += 192;
  float* px1  = ws + o; o += 1024;
  float* py1  = ws + o; o += 1024;
  float* pz1  = ws + o; o += 1024;
  float* px2  = ws + o; o += 8192;
  float* py2  = ws + o; o += 8192;
  float* pz2  = ws + o; o += 8192;
  int*   idxb = (int*)(ws + o); o += (size_t)2 * 4096 * KNN;
  float* ndnb = ws + o; o += (size_t)2 * 4096 * KNN * 3;
  float* fo   = ws + o; o += (size_t)2 * 4096 * 704;
  float* fmA  = ws + o; o += (size_t)2 * 4096 * 64;
  float* fmB  = ws + o; o += (size_t)2 * 4096 * 64;

  float* pc1 = (float*)d_out;                 // (2, 4096, 3)
  float* pc2 = (float*)d_out + 2 * 4096 * 3;  // (2, 32768, 3)

  prep_kernel<<<19, 256, 0, stream>>>(d0, dir1, d2, dir3, dir4, dir5,
                                      sdn0, sdn1, sdn2, sdn3, sdn4, sdn5,
                                      l1a, l1b, l2a, l2b, wc1, wc2,
                                      pts1, px1, py1, pz1);

  // ---- stage 1 (N = 512) ----
  knn_kernel<8, 4><<<2 * 512 / 4, 256, 4 * 64 * 8 * 4, stream>>>(px1, py1, pz1, 512, idxb);
  ndn_kernel<<<(2 * 512 * KNN + 255) / 256, 256, 0, stream>>>(pts1, idxb, ndnb, 512);
  op3d_kernel<<<2 * 512 * 32 / 256, 256, 0, stream>>>(ndnb, sdn0, fmA, 512);          // fm0
  fo_kernel<32><<<2 * 512 / 8, 256, 0, stream>>>(fmA, w1, b1, fo, 512);
  opnd_kernel<<<2 * 512 / 4, 256, 0, stream>>>(ndnb, idxb, fo, sdn1, fmB, 512);       // fm1
  tree_exact_kernel<<<512, 256, 0, stream>>>(fmB, root1, branch1, l1a, l1b,
                                             bias1, pc1, 512);                        // pc1

  // ---- stage 2 (N = 4096) ----
  soa2_kernel<<<32, 256, 0, stream>>>(pc1, px2, py2, pz2);
  knn_kernel<64, 2><<<2 * 4096 / 2, 128, 2 * 64 * 64 * 4, stream>>>(px2, py2, pz2, 4096, idxb);
  ndn_kernel<<<(2 * 4096 * KNN + 255) / 256, 256, 0, stream>>>(pc1, idxb, ndnb, 4096);
  op3d_kernel<<<2 * 4096 * 32 / 256, 256, 0, stream>>>(ndnb, sdn2, fmA, 4096);        // fm2
  fo_kernel<32><<<2 * 4096 / 8, 256, 0, stream>>>(fmA, w3, b3, fo, 4096);
  opnd_kernel<<<2 * 4096 / 4, 256, 0, stream>>>(ndnb, idxb, fo, sdn3, fmB, 4096);     // fm3
  fo_kernel<64><<<2 * 4096 / 8, 256, 0, stream>>>(fmB, w4, b4, fo, 4096);
  opnd_kernel<<<2 * 4096 / 4, 256, 0, stream>>>(ndnb, idxb, fo, sdn4, fmA, 4096);     // fm4
  fo_kernel<64><<<2 * 4096 / 8, 256, 0, stream>>>(fmA, w5, b5, fo, 4096);
  opnd_kernel<<<2 * 4096 / 4, 256, 0, stream>>>(ndnb, idxb, fo, sdn5, fmB, 4096);     // fm5
  tree_kernel<<<4096 / 2, 256, 0, stream>>>(fmB, root2, branch2, wc2, pc2, 4096);     // pc2
}

// Round 9
// 638.501 us; speedup vs baseline: 1.2527x; 1.0263x over previous
//
#include <hip/hip_runtime.h>
#include <hip/hip_bf16.h>
#include <stdint.h>

#define SUPPORT 10
#define KNN 20
#define DEGREE 8

// ---------------------------------------------------------------------------
// prep: normalize all 6 direction matrices (columns over axis 0, sequential
// non-FMA to match np), collapse w_l1 @ w_l2 -> 64x3 (fast pc2 path), and
// transpose pts1 to SoA (px1/py1/pz1) for coalesced kNN loads.
// grid: 19 blocks x 256
// ---------------------------------------------------------------------------
__global__ __launch_bounds__(256) void prep_kernel(
    const float* __restrict__ d0, const float* __restrict__ dir1,
    const float* __restrict__ d2, const float* __restrict__ dir3,
    const float* __restrict__ dir4, const float* __restrict__ dir5,
    float* __restrict__ sdn0, float* __restrict__ sdn1, float* __restrict__ sdn2,
    float* __restrict__ sdn3, float* __restrict__ sdn4, float* __restrict__ sdn5,
    const float* __restrict__ l1a, const float* __restrict__ l1b,
    const float* __restrict__ l2a, const float* __restrict__ l2b,
    float* __restrict__ wc1, float* __restrict__ wc2,
    const float* __restrict__ pts1,
    float* __restrict__ px1, float* __restrict__ py1, float* __restrict__ pz1) {
#pragma clang fp contract(off)
  if (blockIdx.x < 13) {
    int t = blockIdx.x * 256 + threadIdx.x;
    if (t >= 3200) return;
    const float* src; float* dst; int cols; int e;
    if (t < 320)       { src = d0;   dst = sdn0; cols = 320; e = t; }
    else if (t < 960)  { src = dir1; dst = sdn1; cols = 640; e = t - 320; }
    else if (t < 1280) { src = d2;   dst = sdn2; cols = 320; e = t - 960; }
    else if (t < 1920) { src = dir3; dst = sdn3; cols = 640; e = t - 1280; }
    else if (t < 2560) { src = dir4; dst = sdn4; cols = 640; e = t - 1920; }
    else               { src = dir5; dst = sdn5; cols = 640; e = t - 2560; }
    float a = src[e], b = src[cols + e], c = src[2 * cols + e];
    float nrm = sqrtf(a * a + b * b + c * c);
    nrm = fmaxf(nrm, 1e-12f);
    dst[e] = a / nrm; dst[cols + e] = b / nrm; dst[2 * cols + e] = c / nrm;
  } else if (blockIdx.x < 15) {
    int which = blockIdx.x - 13;          // 0 -> wc1, 1 -> wc2
    int tt = threadIdx.x;
    if (tt >= 192) return;
    const float* A  = which ? l2a : l1a;  // (64, 640)
    const float* Bm = which ? l2b : l1b;  // (640, 3)
    float* out = which ? wc2 : wc1;
    int i = tt / 3, c = tt % 3;
    float s = 0.f;
    for (int k = 0; k < 640; ++k) s = fmaf(A[i * 640 + k], Bm[k * 3 + c], s);
    out[i * 3 + c] = s;
  } else {
    int t = (blockIdx.x - 15) * 256 + threadIdx.x;  // 0..1023 over 2*512 pts
    if (t >= 1024) return;
    px1[t] = pts1[t * 3];
    py1[t] = pts1[t * 3 + 1];
    pz1[t] = pts1[t * 3 + 2];
  }
}

// ---------------------------------------------------------------------------
// kNN + ndn fused: known-good LDS selection (bit-identical order), each lane
// r-1 keeps round-r winner; epilogue writes idx coalesced and computes the
// ndn row (same contract-off formula as the old ndn kernel) in-place.
// MPER = N/64. Dyn LDS = WAVES*64*MPER*4 bytes.
// ---------------------------------------------------------------------------
template <int MPER, int WAVES>
__global__ __launch_bounds__(WAVES * 64) void knn_kernel(
    const float* __restrict__ px, const float* __restrict__ py,
    const float* __restrict__ pz, int N, int* __restrict__ idx_out,
    float* __restrict__ ndn) {
#pragma clang fp contract(off)
  extern __shared__ uint32_t kbuf[];
  int w = threadIdx.x >> 6, lane = threadIdx.x & 63;
  int g = blockIdx.x * WAVES + w;           // global node id in [0, 2N)
  int b = g / N, n = g % N;
  volatile uint32_t* K = kbuf + (size_t)w * 64 * MPER;
  const float* PX = px + (size_t)b * N;
  const float* PY = py + (size_t)b * N;
  const float* PZ = pz + (size_t)b * N;

  float nx = PX[n], ny = PY[n], nz = PZ[n];
  float qn = nx * nx + ny * ny + nz * nz;

  unsigned long long mymin = ~0ull;
  for (int j = 0; j < MPER; ++j) {
    int m = j * 64 + lane;
    float mx = PX[m], my = PY[m], mz = PZ[m];
    float inner = nx * mx + ny * my + nz * mz;
    float qm = mx * mx + my * my + mz * mz;
    float d = (qn - 2.0f * inner) + qm;
    uint32_t u = __float_as_uint(d);
    u ^= (u & 0x80000000u) ? 0xFFFFFFFFu : 0x80000000u;  // order-preserving flip
    K[lane * MPER + (j ^ (lane & (MPER - 1)))] = u;
    unsigned long long key = ((unsigned long long)u << 32) | (unsigned)m;
    mymin = key < mymin ? key : mymin;
  }
  unsigned pick = 0;
  for (int r = 0; r < 21; ++r) {
    unsigned long long best = mymin;
#pragma unroll
    for (int s = 1; s < 64; s <<= 1) {
      unsigned long long o = __shfl_xor(best, s, 64);
      best = o < best ? o : best;
    }
    unsigned m = (unsigned)best;
    if (r > 0 && lane == r - 1) pick = m;
    if (r == 20) break;
    int owner = m & 63, slot = m >> 6;
    if (lane == slot) K[owner * MPER + (slot ^ (owner & (MPER - 1)))] = 0xFFFFFFFFu;
    unsigned long long cand = ~0ull;
    if (lane < MPER) {
      uint32_t v = K[owner * MPER + (lane ^ (owner & (MPER - 1)))];
      cand = ((unsigned long long)v << 32) | (unsigned)(lane * 64 + owner);
    }
#pragma unroll
    for (int s = 1; s < 64; s <<= 1) {
      unsigned long long o = __shfl_xor(cand, s, 64);
      cand = o < cand ? o : cand;
    }
    if (lane == owner) mymin = cand;
  }
  if (lane < KNN) {
    idx_out[(size_t)g * KNN + lane] = (int)pick;
    float mx = PX[pick], my = PY[pick], mz = PZ[pick];
    float dx = mx - nx, dy = my - ny, dz = mz - nz;
    float nr = sqrtf(dx * dx + dy * dy + dz * dz);
    nr = fmaxf(nr, 1e-12f);
    size_t base = (size_t)g * 60 + (size_t)lane * 3;
    ndn[base] = dx / nr; ndn[base + 1] = dy / nr; ndn[base + 2] = dz / nr;
  }
}

// ---------------------------------------------------------------------------
// op3d + fo fused: block of 8 nodes. Phase 1: thread (gg=t>>5, c=t&31)
// computes op3d (identical math/order) into LDS fL. Phase 2: identical fo
// matmul (K=32, sequential fmaf) reading fL instead of a global fm0.
// ---------------------------------------------------------------------------
__global__ __launch_bounds__(256) void op3dfo_kernel(const float* __restrict__ ndn,
                                                     const float* __restrict__ sdn,
                                                     const float* __restrict__ wmat,
                                                     const float* __restrict__ bias,
                                                     float* __restrict__ fo, int N) {
#pragma clang fp contract(off)
  __shared__ float ndL[8 * 60];
  __shared__ float fL[8 * 32];
  int t = threadIdx.x;
  int gbase = blockIdx.x * 8;
  for (int i = t; i < 8 * 60; i += 256) ndL[i] = ndn[(size_t)gbase * 60 + i];
  __syncthreads();
  {
    int gg = t >> 5, c = t & 31;
    const float* nd = ndL + gg * 60;
    float sv0[SUPPORT], sv1[SUPPORT], sv2[SUPPORT], mm[SUPPORT];
#pragma unroll
    for (int s = 0; s < SUPPORT; ++s) {
      sv0[s] = sdn[s * 32 + c];
      sv1[s] = sdn[320 + s * 32 + c];
      sv2[s] = sdn[640 + s * 32 + c];
      mm[s] = 0.f;
    }
    for (int k = 0; k < KNN; ++k) {
      float nx = nd[k * 3], ny = nd[k * 3 + 1], nz = nd[k * 3 + 2];
#pragma unroll
      for (int s = 0; s < SUPPORT; ++s) {
        float th = nx * sv0[s] + ny * sv1[s] + nz * sv2[s];
        mm[s] = fmaxf(mm[s], th);
      }
    }
    float acc = 0.f;
#pragma unroll
    for (int s = 0; s < SUPPORT; ++s) acc += mm[s];
    fL[gg * 32 + c] = acc;
  }
  __syncthreads();
  float a0[8], a1[8], a2[8];
#pragma unroll
  for (int gg = 0; gg < 8; ++gg) { a0[gg] = 0.f; a1[gg] = 0.f; a2[gg] = 0.f; }
  bool has3 = (t < 192);
  for (int i = 0; i < 32; ++i) {
    float w0 = wmat[i * 704 + t];
    float w1 = wmat[i * 704 + t + 256];
    float w2 = has3 ? wmat[i * 704 + t + 512] : 0.f;
#pragma unroll
    for (int gg = 0; gg < 8; ++gg) {
      float f = fL[gg * 32 + i];
      a0[gg] = fmaf(f, w0, a0[gg]);
      a1[gg] = fmaf(f, w1, a1[gg]);
      a2[gg] = fmaf(f, w2, a2[gg]);
    }
  }
  float b0 = bias[t], b1 = bias[t + 256], b2 = has3 ? bias[t + 512] : 0.f;
#pragma unroll
  for (int gg = 0; gg < 8; ++gg) {
    size_t base = (size_t)(gbase + gg) * 704;
    fo[base + t] = a0[gg] + b0;
    fo[base + t + 256] = a1[gg] + b1;
    if (has3) fo[base + t + 512] = a2[gg] + b2;
  }
}

// ---------------------------------------------------------------------------
// fo = feat @ W + b (K=64): sequential-k fmaf chain, 8 nodes/block.
// ---------------------------------------------------------------------------
__global__ __launch_bounds__(256) void fo_kernel(const float* __restrict__ feat,
                                                 const float* __restrict__ wmat,
                                                 const float* __restrict__ bias,
                                                 float* __restrict__ fo, int N) {
  __shared__ float fL[8 * 64];
  int t = threadIdx.x;
  int gbase = blockIdx.x * 8;
  for (int i = t; i < 8 * 64; i += 256) fL[i] = feat[(size_t)gbase * 64 + i];
  __syncthreads();
  float a0[8], a1[8], a2[8];
#pragma unroll
  for (int gg = 0; gg < 8; ++gg) { a0[gg] = 0.f; a1[gg] = 0.f; a2[gg] = 0.f; }
  bool has3 = (t < 192);
  for (int i = 0; i < 64; ++i) {
    float w0 = wmat[i * 704 + t];
    float w1 = wmat[i * 704 + t + 256];
    float w2 = has3 ? wmat[i * 704 + t + 512] : 0.f;
#pragma unroll
    for (int gg = 0; gg < 8; ++gg) {
      float f = fL[gg * 64 + i];
      a0[gg] = fmaf(f, w0, a0[gg]);
      a1[gg] = fmaf(f, w1, a1[gg]);
      a2[gg] = fmaf(f, w2, a2[gg]);
    }
  }
  float b0 = bias[t], b1 = bias[t + 256], b2 = has3 ? bias[t + 512] : 0.f;
#pragma unroll
  for (int gg = 0; gg < 8; ++gg) {
    size_t base = (size_t)(gbase + gg) * 704;
    fo[base + t] = a0[gg] + b0;
    fo[base + t + 256] = a1[gg] + b1;
    if (has3) fo[base + t + 512] = a2[gg] + b2;
  }
}

// ---------------------------------------------------------------------------
// opnd: one wave per node, lane = output channel (64). Chunked inverse-XCD
// block swizzle keeps each XCD's fo gather window L2-resident (R8: -11 us).
// ---------------------------------------------------------------------------
__global__ __launch_bounds__(256) void opnd_kernel(const float* __restrict__ ndn,
                                                   const int* __restrict__ idx,
                                                   const float* __restrict__ fo,
                                                   const float* __restrict__ sdn,
                                                   float* __restrict__ fm, int N) {
#pragma clang fp contract(off)
  __shared__ float ndL[4][64];
  __shared__ int offL[4][24];
  int nb = gridDim.x;                                   // multiple of 8
  int lb = (blockIdx.x & 7) * (nb >> 3) + (blockIdx.x >> 3);
  int w = threadIdx.x >> 6, lane = threadIdx.x & 63;
  int g = lb * 4 + w;
  if (lane < 60) ndL[w][lane] = ndn[(size_t)g * 60 + lane];
  if (lane < KNN) offL[w][lane] = ((g / N) * N + idx[(size_t)g * KNN + lane]) * 704 + 64;
  __syncthreads();
  const float* ndw = ndL[w];
  const int* offw = offL[w];
  float sv0[SUPPORT], sv1[SUPPORT], sv2[SUPPORT], mm[SUPPORT];
#pragma unroll
  for (int s = 0; s < SUPPORT; ++s) {
    sv0[s] = sdn[s * 64 + lane];
    sv1[s] = sdn[640 + s * 64 + lane];
    sv2[s] = sdn[1280 + s * 64 + lane];
    mm[s] = -__builtin_inff();
  }
  for (int k = 0; k < KNN; ++k) {
    float nx = ndw[k * 3], ny = ndw[k * 3 + 1], nz = ndw[k * 3 + 2];
    int off = offw[k];
#pragma unroll
    for (int s = 0; s < SUPPORT; ++s) {
      float t = fmaxf(nx * sv0[s] + ny * sv1[s] + nz * sv2[s], 0.f);
      float f = fo[(size_t)off + s * 64 + lane];
      mm[s] = fmaxf(mm[s], t * f);
    }
  }
  float acc = 0.f;
#pragma unroll
  for (int s = 0; s < SUPPORT; ++s) acc += mm[s];
  float fc = fo[(size_t)g * 704 + lane];
  float v = fc + acc;
  fm[(size_t)g * 64 + lane] = fmaxf(v, 0.f);
}

// ---------------------------------------------------------------------------
// tree_gcn EXACT (pc1): mirrors np op-by-op (pc1 feeds stage-2 kNN). Epilogue
// also scatters pc1 into SoA px2/py2/pz2 (same v bits) — soa2 fused away.
// ---------------------------------------------------------------------------
__global__ __launch_bounds__(256) void tree_exact_kernel(
    const float* __restrict__ x, const float* __restrict__ wroot,
    const float* __restrict__ wb, const float* __restrict__ l1,
    const float* __restrict__ l2, const float* __restrict__ bias,
    float* __restrict__ out, int node,
    float* __restrict__ px2, float* __restrict__ py2, float* __restrict__ pz2) {
#pragma clang fp contract(off)
  __shared__ float xL[2][64];
  __shared__ float brL[2][512];
  __shared__ float tL[16][640];
  __shared__ float rootv[2][3];
  int n = blockIdx.x, t = threadIdx.x;
  if (t < 128) xL[t >> 6][t & 63] = x[(size_t)(t >> 6) * node * 64 + (size_t)n * 64 + (t & 63)];
  __syncthreads();
  {
    const float* wrow = wb + (size_t)n * 64 * 512;
    int j0 = 2 * t;
    float a00 = 0.f, a01 = 0.f, a10 = 0.f, a11 = 0.f;
    for (int i = 0; i < 64; ++i) {
      float w0 = wrow[(size_t)i * 512 + j0];
      float w1 = wrow[(size_t)i * 512 + j0 + 1];
      float f0 = xL[0][i], f1 = xL[1][i];
      a00 = a00 + f0 * w0; a01 = a01 + f0 * w1;
      a10 = a10 + f1 * w0; a11 = a11 + f1 * w1;
    }
    brL[0][j0]     = a00 >= 0.f ? a00 : 0.2f * a00;
    brL[0][j0 + 1] = a01 >= 0.f ? a01 : 0.2f * a01;
    brL[1][j0]     = a10 >= 0.f ? a10 : 0.2f * a10;
    brL[1][j0 + 1] = a11 >= 0.f ? a11 : 0.2f * a11;
  }
  if (t < 6) {
    int b = t / 3, c = t % 3;
    float r = 0.f;
    for (int i = 0; i < 64; ++i) r = fmaf(xL[b][i], wroot[i * 3 + c], r);
    rootv[b][c] = r;
  }
  __syncthreads();
#pragma unroll 4
  for (int u = 0; u < 40; ++u) {        // 16*640 / 256
    int e = u * 256 + t;
    int p = e / 640, j = e % 640;       // p: b = p>>3, d = p&7
    const float* brow = brL[p >> 3] + (p & 7) * 64;
    float acc = 0.f;
    for (int i = 0; i < 64; ++i)
      acc = fmaf(brow[i], l1[i * 640 + j], acc);
    tL[p][j] = acc;
  }
  __syncthreads();
  if (t < 48) {
    int p = t / 3, c = t % 3, b = p >> 3, d = p & 7;
    float s = 0.f;
    for (int j = 0; j < 640; ++j) s = fmaf(tL[p][j], l2[j * 3 + c], s);
    float v = rootv[b][c] + s;
    v = v + bias[d * 3 + c];
    v = v >= 0.f ? v : 0.2f * v;
    out[((size_t)b * node * DEGREE + (size_t)n * DEGREE + d) * 3 + c] = v;
    int p2 = b * node * DEGREE + n * DEGREE + d;
    if (c == 0) px2[p2] = v; else if (c == 1) py2[p2] = v; else pz2[p2] = v;
  }
}

// ---------------------------------------------------------------------------
// tree_gcn FAST (pc2): collapsed w_l1@w_l2, HBM-bound on the w_branch stream.
// 2 nodes/block, float4 weight loads. Accumulation order over i unchanged.
// ---------------------------------------------------------------------------
__global__ __launch_bounds__(256) void tree_kernel(const float* __restrict__ x,
                                                   const float* __restrict__ wroot,
                                                   const float* __restrict__ wb,
                                                   const float* __restrict__ wc,
                                                   float* __restrict__ out,
                                                   int node) {
  __shared__ float xL[2][2][64];     // [node-sub][batch][i]
  __shared__ float brL[2][2][512];   // [node-sub][batch][j]
  int t = threadIdx.x;
  int n0 = blockIdx.x * 2;
  {
    int which = t >> 6;              // 0..3: nsub = which>>1, batch = which&1
    int ns = which >> 1, bb = which & 1;
    xL[ns][bb][t & 63] = x[(size_t)bb * node * 64 + (size_t)(n0 + ns) * 64 + (t & 63)];
  }
  __syncthreads();
  int ns = t >> 7;                   // node sub-index (0..1)
  int j0 = (t & 127) * 4;            // 4 consecutive cols of 512
  const float* wrow = wb + (size_t)(n0 + ns) * 64 * 512;
  float a0x = 0.f, a0y = 0.f, a0z = 0.f, a0w = 0.f;
  float a1x = 0.f, a1y = 0.f, a1z = 0.f, a1w = 0.f;
  for (int i = 0; i < 64; ++i) {
    float4 wv = *(const float4*)(wrow + (size_t)i * 512 + j0);
    float f0 = xL[ns][0][i], f1 = xL[ns][1][i];
    a0x += f0 * wv.x; a0y += f0 * wv.y; a0z += f0 * wv.z; a0w += f0 * wv.w;
    a1x += f1 * wv.x; a1y += f1 * wv.y; a1z += f1 * wv.z; a1w += f1 * wv.w;
  }
  brL[ns][0][j0]     = a0x >= 0.f ? a0x : 0.2f * a0x;
  brL[ns][0][j0 + 1] = a0y >= 0.f ? a0y : 0.2f * a0y;
  brL[ns][0][j0 + 2] = a0z >= 0.f ? a0z : 0.2f * a0z;
  brL[ns][0][j0 + 3] = a0w >= 0.f ? a0w : 0.2f * a0w;
  brL[ns][1][j0]     = a1x >= 0.f ? a1x : 0.2f * a1x;
  brL[ns][1][j0 + 1] = a1y >= 0.f ? a1y : 0.2f * a1y;
  brL[ns][1][j0 + 2] = a1z >= 0.f ? a1z : 0.2f * a1z;
  brL[ns][1][j0 + 3] = a1w >= 0.f ? a1w : 0.2f * a1w;
  __syncthreads();
  if (t < 96) {
    int nsub = t / 48, rem = t % 48;
    int b = rem / 24, r2 = rem % 24, d = r2 / 3, c = r2 % 3;
    float root = 0.f, brs = 0.f;
    for (int i = 0; i < 64; ++i) {
      root = fmaf(xL[nsub][b][i], wroot[i * 3 + c], root);
      brs  = fmaf(brL[nsub][b][d * 64 + i], wc[i * 3 + c], brs);
    }
    float v = root + brs;
    out[((size_t)b * node * DEGREE + (size_t)(n0 + nsub) * DEGREE + d) * 3 + c] = v;
  }
}

// ---------------------------------------------------------------------------
extern "C" void kernel_launch(void* const* d_in, const int* in_sizes, int n_in,
                              void* d_out, int out_size, void* d_ws, size_t ws_size,
                              hipStream_t stream) {
  const float* pts1    = (const float*)d_in[0];
  const float* d0      = (const float*)d_in[1];
  const float* w1      = (const float*)d_in[2];
  const float* b1      = (const float*)d_in[3];
  const float* dir1    = (const float*)d_in[4];
  const float* d2      = (const float*)d_in[5];
  const float* w3      = (const float*)d_in[6];
  const float* b3      = (const float*)d_in[7];
  const float* dir3    = (const float*)d_in[8];
  const float* w4      = (const float*)d_in[9];
  const float* b4      = (const float*)d_in[10];
  const float* dir4    = (const float*)d_in[11];
  const float* w5      = (const float*)d_in[12];
  const float* b5      = (const float*)d_in[13];
  const float* dir5    = (const float*)d_in[14];
  const float* root1   = (const float*)d_in[15];
  const float* branch1 = (const float*)d_in[16];
  const float* l1a     = (const float*)d_in[17];
  const float* l1b     = (const float*)d_in[18];
  const float* bias1   = (const float*)d_in[19];
  const float* root2   = (const float*)d_in[20];
  const float* branch2 = (const float*)d_in[21];
  const float* l2a     = (const float*)d_in[22];
  const float* l2b     = (const float*)d_in[23];

  // workspace layout (floats) — total ~30 MB
  float* ws = (float*)d_ws;
  size_t o = 0;
  float* sdn0 = ws + o; o += 960;
  float* sdn1 = ws + o; o += 1920;
  float* sdn2 = ws + o; o += 960;
  float* sdn3 = ws + o; o += 1920;
  float* sdn4 = ws + o; o += 1920;
  float* sdn5 = ws + o; o += 1920;
  float* wc1  = ws + o; o += 192;
  float* wc2  = ws + o; o += 192;
  float* px1  = ws + o; o += 1024;
  float* py1  = ws + o; o += 1024;
  float* pz1  = ws + o; o += 1024;
  float* px2  = ws + o; o += 8192;
  float* py2  = ws + o; o += 8192;
  float* pz2  = ws + o; o += 8192;
  int*   idxb = (int*)(ws + o); o += (size_t)2 * 4096 * KNN;
  float* ndnb = ws + o; o += (size_t)2 * 4096 * KNN * 3;
  float* fo   = ws + o; o += (size_t)2 * 4096 * 704;
  float* fmA  = ws + o; o += (size_t)2 * 4096 * 64;
  float* fmB  = ws + o; o += (size_t)2 * 4096 * 64;

  float* pc1 = (float*)d_out;                 // (2, 4096, 3)
  float* pc2 = (float*)d_out + 2 * 4096 * 3;  // (2, 32768, 3)

  prep_kernel<<<19, 256, 0, stream>>>(d0, dir1, d2, dir3, dir4, dir5,
                                      sdn0, sdn1, sdn2, sdn3, sdn4, sdn5,
                                      l1a, l1b, l2a, l2b, wc1, wc2,
                                      pts1, px1, py1, pz1);

  // ---- stage 1 (N = 512) ----
  knn_kernel<8, 4><<<2 * 512 / 4, 256, 4 * 64 * 8 * 4, stream>>>(px1, py1, pz1, 512, idxb, ndnb);
  op3dfo_kernel<<<2 * 512 / 8, 256, 0, stream>>>(ndnb, sdn0, w1, b1, fo, 512);
  opnd_kernel<<<2 * 512 / 4, 256, 0, stream>>>(ndnb, idxb, fo, sdn1, fmB, 512);       // fm1
  tree_exact_kernel<<<512, 256, 0, stream>>>(fmB, root1, branch1, l1a, l1b,
                                             bias1, pc1, 512, px2, py2, pz2);         // pc1 + SoA

  // ---- stage 2 (N = 4096) ----
  knn_kernel<64, 2><<<2 * 4096 / 2, 128, 2 * 64 * 64 * 4, stream>>>(px2, py2, pz2, 4096, idxb, ndnb);
  op3dfo_kernel<<<2 * 4096 / 8, 256, 0, stream>>>(ndnb, sdn2, w3, b3, fo, 4096);
  opnd_kernel<<<2 * 4096 / 4, 256, 0, stream>>>(ndnb, idxb, fo, sdn3, fmB, 4096);     // fm3
  fo_kernel<<<2 * 4096 / 8, 256, 0, stream>>>(fmB, w4, b4, fo, 4096);
  opnd_kernel<<<2 * 4096 / 4, 256, 0, stream>>>(ndnb, idxb, fo, sdn4, fmA, 4096);     // fm4
  fo_kernel<<<2 * 4096 / 8, 256, 0, stream>>>(fmA, w5, b5, fo, 4096);
  opnd_kernel<<<2 * 4096 / 4, 256, 0, stream>>>(ndnb, idxb, fo, sdn5, fmB, 4096);     // fm5
  tree_kernel<<<4096 / 2, 256, 0, stream>>>(fmB, root2, branch2, wc2, pc2, 4096);     // pc2
}